// Round 3
// baseline (965.004 us; speedup 1.0000x reference)
//
#include <hip/hip_runtime.h>

typedef __attribute__((ext_vector_type(8))) short short8;
typedef __attribute__((ext_vector_type(4))) float f32x4;
typedef __attribute__((ext_vector_type(4))) int int4v;
typedef __attribute__((ext_vector_type(4))) unsigned short ushort4v;

#define SCALE_F 0.0625f   // C^-0.5 = 256^-0.5
#define EPS_F 1e-5f

__device__ __forceinline__ float bf2f(unsigned short u) {
  unsigned int i = ((unsigned int)u) << 16;
  return __builtin_bit_cast(float, i);
}
__device__ __forceinline__ unsigned short f2bf(float f) {
  unsigned int i = __builtin_bit_cast(unsigned int, f);
  i += 0x7fffu + ((i >> 16) & 1u);
  return (unsigned short)(i >> 16);
}

__device__ __forceinline__ void gload_lds16(const unsigned short* g, unsigned short* l) {
  __builtin_amdgcn_global_load_lds(
      (const __attribute__((address_space(1))) void*)g,
      (__attribute__((address_space(3))) void*)l, 16, 0, 0);
}

// ---- cast weight [K,N] f32 -> [N,K] bf16 (transposed) ----
template<int K, int N>
__global__ void cast_wt(const float* __restrict__ src, unsigned short* __restrict__ dst) {
  int id = blockIdx.x * 256 + threadIdx.x;          // id = n*K + k
  if (id >= K * N) return;
  int k = id % K, n = id / K;
  dst[id] = f2bf(src[(size_t)k * N + n]);
}

// ---- precompute relative-position bias [head][i][j] ----
__global__ void build_relb(const float* __restrict__ table, float* __restrict__ relb) {
  int id = blockIdx.x * 256 + threadIdx.x;          // 8*64*64
  int h = id >> 12, i = (id >> 6) & 63, j = id & 63;
  int dy = (i >> 3) - (j >> 3) + 7;
  int dx = (i & 7) - (j & 7) + 7;
  relb[id] = table[(dy * 15 + dx) * 8 + h];
}

// ---- window partition + LN1: x[B,C,64,64] -> h bf16 [M,256] ----
__global__ __launch_bounds__(256) void part_ln1(
    const float* __restrict__ x, const float* __restrict__ g, const float* __restrict__ bb,
    unsigned short* __restrict__ h) {
  int m = blockIdx.x * 4 + (threadIdx.x >> 6);
  int l = threadIdx.x & 63;
  int b = m >> 12, gg = (m >> 6) & 63, s = m & 63;
  int sp = ((gg >> 3) * 8 + (s >> 3)) * 64 + (gg & 7) * 8 + (s & 7);
  const float* xp = x + (size_t)b * 256 * 4096 + sp;
  float v[4];
  float sum = 0.f, ss = 0.f;
#pragma unroll
  for (int j = 0; j < 4; j++) {
    v[j] = xp[(size_t)(l * 4 + j) * 4096];
    sum += v[j]; ss += v[j] * v[j];
  }
#pragma unroll
  for (int d = 1; d < 64; d <<= 1) {
    sum += __shfl_xor(sum, d, 64);
    ss  += __shfl_xor(ss, d, 64);
  }
  float mu = sum * (1.f / 256.f);
  float var = ss * (1.f / 256.f) - mu * mu;
  float rs = rsqrtf(var + EPS_F);
  ushort4v oh;
#pragma unroll
  for (int j = 0; j < 4; j++) {
    int c = l * 4 + j;
    oh[j] = f2bf((v[j] - mu) * rs * g[c] + bb[c]);
  }
  *(ushort4v*)(h + (size_t)m * 256 + l * 4) = oh;
}

// ---- LN2: x2 bf16 [M,256] -> h2 bf16 [M,256] ----
__global__ __launch_bounds__(256) void ln2k(
    const unsigned short* __restrict__ x2, const float* __restrict__ g, const float* __restrict__ bb,
    unsigned short* __restrict__ h2) {
  int m = blockIdx.x * 4 + (threadIdx.x >> 6);
  int l = threadIdx.x & 63;
  ushort4v u = *(const ushort4v*)(x2 + (size_t)m * 256 + l * 4);
  float v[4];
  float sum = 0.f, ss = 0.f;
#pragma unroll
  for (int j = 0; j < 4; j++) { v[j] = bf2f(u[j]); sum += v[j]; ss += v[j] * v[j]; }
#pragma unroll
  for (int d = 1; d < 64; d <<= 1) {
    sum += __shfl_xor(sum, d, 64);
    ss  += __shfl_xor(ss, d, 64);
  }
  float mu = sum * (1.f / 256.f);
  float var = ss * (1.f / 256.f) - mu * mu;
  float rs = rsqrtf(var + EPS_F);
  ushort4v oh;
#pragma unroll
  for (int j = 0; j < 4; j++) {
    int c = l * 4 + j;
    oh[j] = f2bf((v[j] - mu) * rs * g[c] + bb[c]);
  }
  *(ushort4v*)(h2 + (size_t)m * 256 + l * 4) = oh;
}

// ---- GEMM: A bf16 [rows,K] x Bt bf16 [N,K] -> out, 128x128 tile, 4 waves ----
// m97 structure: global_load_lds width-16 staging into linear [128][64] LDS tiles.
enum { EPI_QKV = 0, EPI_MERGE = 1, EPI_GELU = 2, EPI_OUT = 3 };

template<int EPI>
__global__ __launch_bounds__(256) void gemm_bt(
    const unsigned short* __restrict__ A, const unsigned short* __restrict__ Bt,
    const float* __restrict__ bias, const void* __restrict__ res,
    void* __restrict__ out, int K, int N, long m_base) {
  __shared__ __align__(16) unsigned short As[128 * 64];
  __shared__ __align__(16) unsigned short Bs[128 * 64];
  const int tid = threadIdx.x;
  const int l15 = tid & 15, lhi = (tid & 63) >> 4;
  const int wid = tid >> 6, wm = wid >> 1, wn = wid & 1;
  const size_t m0 = (size_t)blockIdx.x * 128;
  const int n0 = blockIdx.y * 128;
  const int row_s = tid >> 3, kc8 = (tid & 7) * 8;   // staging coords

  f32x4 acc[4][4];
#pragma unroll
  for (int i = 0; i < 4; i++)
#pragma unroll
    for (int j = 0; j < 4; j++) acc[i][j] = (f32x4){0.f, 0.f, 0.f, 0.f};

  for (int k0 = 0; k0 < K; k0 += 64) {
    __syncthreads();   // previous tile fully consumed before overwrite
#pragma unroll
    for (int i = 0; i < 4; i++) {
      int row = i * 32 + row_s;
      gload_lds16(A + (m0 + row) * (size_t)K + k0 + kc8, &As[(i * 256 + tid) * 8]);
      gload_lds16(Bt + (size_t)(n0 + row) * (size_t)K + k0 + kc8, &Bs[(i * 256 + tid) * 8]);
    }
    __syncthreads();   // drains vmcnt -> tile resident
#pragma unroll
    for (int ks = 0; ks < 2; ks++) {
      short8 af[4], bfr[4];
#pragma unroll
      for (int t = 0; t < 4; t++) {
        af[t]  = *(const short8*)(&As[(wm * 64 + t * 16 + l15) * 64 + ks * 32 + lhi * 8]);
        bfr[t] = *(const short8*)(&Bs[(wn * 64 + t * 16 + l15) * 64 + ks * 32 + lhi * 8]);
      }
#pragma unroll
      for (int mt = 0; mt < 4; mt++)
#pragma unroll
        for (int nt = 0; nt < 4; nt++)
          acc[mt][nt] = __builtin_amdgcn_mfma_f32_16x16x32_bf16(af[mt], bfr[nt], acc[mt][nt], 0, 0, 0);
    }
  }

#pragma unroll
  for (int mt = 0; mt < 4; mt++) {
#pragma unroll
    for (int nt = 0; nt < 4; nt++) {
#pragma unroll
      for (int r = 0; r < 4; r++) {
        size_t gml = m0 + wm * 64 + mt * 16 + lhi * 4 + r;   // chunk-local row
        size_t gm = gml + (size_t)m_base;                     // global row
        int gn = n0 + wn * 64 + nt * 16 + l15;
        float v = acc[mt][nt][r] + bias[gn];
        if (EPI == EPI_QKV) {
          ((unsigned short*)out)[gml * (size_t)N + gn] = f2bf(v);
        } else if (EPI == EPI_MERGE) {
          int bi = (int)(gm >> 12), gg = (int)((gm >> 6) & 63), s = (int)(gm & 63);
          size_t sp = ((gg >> 3) * 8 + (s >> 3)) * 64 + (gg & 7) * 8 + (s & 7);
          v += ((const float*)res)[((size_t)(bi * 256 + gn)) * 4096 + sp];
          ((unsigned short*)out)[gm * 256 + gn] = f2bf(v);
        } else if (EPI == EPI_GELU) {
          float gl = 0.5f * v * (1.f + erff(v * 0.70710678118f));
          ((unsigned short*)out)[gml * (size_t)N + gn] = f2bf(gl);
        } else {  // EPI_OUT: + x2 residual, departition to [B,C,64,64] f32
          v += bf2f(((const unsigned short*)res)[gm * 256 + gn]);
          int bi = (int)(gm >> 12), gg = (int)((gm >> 6) & 63), s = (int)(gm & 63);
          size_t o = (size_t)(bi * 256 + gn) * 4096 +
                     ((gg >> 3) * 8 + (s >> 3)) * 64 + (gg & 7) * 8 + (s & 7);
          ((float*)out)[o] = v;
        }
      }
    }
  }
}

// ---- attention: one wave per (window, head) ----
__global__ __launch_bounds__(64) void attn_k(
    const unsigned short* __restrict__ qkv, const float* __restrict__ relb,
    unsigned short* __restrict__ o) {
  __shared__ __align__(16) unsigned short p_lds[64 * 72];
  __shared__ __align__(16) unsigned short vt_lds[32 * 72];
  const int l = threadIdx.x;
  const int l15 = l & 15, lhi = l >> 4;
  const int w = blockIdx.x, head = blockIdx.y;
  const unsigned short* base = qkv + (size_t)w * 64 * 768 + head * 32;

  short8 aq[4], bk[4];
#pragma unroll
  for (int t = 0; t < 4; t++) {
    aq[t] = *(const short8*)(base + (t * 16 + l15) * 768 + lhi * 8);
    bk[t] = *(const short8*)(base + 256 + (t * 16 + l15) * 768 + lhi * 8);
  }
  f32x4 s[4][4];
#pragma unroll
  for (int i = 0; i < 4; i++)
#pragma unroll
    for (int j = 0; j < 4; j++) s[i][j] = (f32x4){0.f, 0.f, 0.f, 0.f};
#pragma unroll
  for (int mt = 0; mt < 4; mt++)
#pragma unroll
    for (int nt = 0; nt < 4; nt++)
      s[mt][nt] = __builtin_amdgcn_mfma_f32_16x16x32_bf16(aq[mt], bk[nt], s[mt][nt], 0, 0, 0);

  const float* rb = relb + head * 4096;
  float rsum[4][4];
#pragma unroll
  for (int mt = 0; mt < 4; mt++) {
#pragma unroll
    for (int r = 0; r < 4; r++) {
      int row = mt * 16 + lhi * 4 + r;
      float vv[4];
      float vmax = -1e30f;
#pragma unroll
      for (int nt = 0; nt < 4; nt++) {
        int col = nt * 16 + l15;
        float v = s[mt][nt][r] * SCALE_F + rb[row * 64 + col];
        vv[nt] = v;
        vmax = fmaxf(vmax, v);
      }
#pragma unroll
      for (int d = 1; d < 16; d <<= 1) vmax = fmaxf(vmax, __shfl_xor(vmax, d, 64));
      float sum = 0.f;
#pragma unroll
      for (int nt = 0; nt < 4; nt++) {
        float p = __expf(vv[nt] - vmax);
        sum += p;
        p_lds[row * 72 + nt * 16 + l15] = f2bf(p);
      }
#pragma unroll
      for (int d = 1; d < 16; d <<= 1) sum += __shfl_xor(sum, d, 64);
      rsum[mt][r] = 1.f / sum;
    }
  }

  // stage v^T: vt[dh][token]
#pragma unroll
  for (int j = 0; j < 4; j++) {
    short8 vv = *(const short8*)(base + 512 + l * 768 + j * 8);
#pragma unroll
    for (int e = 0; e < 8; e++)
      vt_lds[(j * 8 + e) * 72 + l] = (unsigned short)vv[e];
  }
  __syncthreads();

  f32x4 o2[4][2];
#pragma unroll
  for (int i = 0; i < 4; i++) { o2[i][0] = (f32x4){0.f,0.f,0.f,0.f}; o2[i][1] = (f32x4){0.f,0.f,0.f,0.f}; }
#pragma unroll
  for (int ks = 0; ks < 2; ks++) {
    short8 ap[4], bv[2];
#pragma unroll
    for (int t = 0; t < 4; t++)
      ap[t] = *(const short8*)(&p_lds[(t * 16 + l15) * 72 + ks * 32 + lhi * 8]);
#pragma unroll
    for (int t = 0; t < 2; t++)
      bv[t] = *(const short8*)(&vt_lds[(t * 16 + l15) * 72 + ks * 32 + lhi * 8]);
#pragma unroll
    for (int mt = 0; mt < 4; mt++)
#pragma unroll
      for (int n2 = 0; n2 < 2; n2++)
        o2[mt][n2] = __builtin_amdgcn_mfma_f32_16x16x32_bf16(ap[mt], bv[n2], o2[mt][n2], 0, 0, 0);
  }
#pragma unroll
  for (int mt = 0; mt < 4; mt++)
#pragma unroll
    for (int n2 = 0; n2 < 2; n2++)
#pragma unroll
      for (int r = 0; r < 4; r++) {
        int row = mt * 16 + lhi * 4 + r;
        int dh = n2 * 16 + l15;
        o[((size_t)w * 64 + row) * 256 + head * 32 + dh] = f2bf(o2[mt][n2][r] * rsum[mt][r]);
      }
}

extern "C" void kernel_launch(void* const* d_in, const int* in_sizes, int n_in,
                              void* d_out, int out_size, void* d_ws, size_t ws_size,
                              hipStream_t stream) {
  (void)in_sizes; (void)n_in; (void)out_size;
  const float* x          = (const float*)d_in[0];
  const float* ln1_g      = (const float*)d_in[1];
  const float* ln1_b      = (const float*)d_in[2];
  const float* qkv_w      = (const float*)d_in[3];
  const float* qkv_b      = (const float*)d_in[4];
  const float* merge_w    = (const float*)d_in[5];
  const float* merge_b    = (const float*)d_in[6];
  const float* bias_table = (const float*)d_in[7];
  const float* ln2_g      = (const float*)d_in[8];
  const float* ln2_b      = (const float*)d_in[9];
  const float* mlp_w1     = (const float*)d_in[10];
  const float* mlp_b1     = (const float*)d_in[11];
  const float* mlp_w2     = (const float*)d_in[12];
  const float* mlp_b2     = (const float*)d_in[13];

  const size_t MB = 1024ull * 1024ull;
  char* ws = (char*)d_ws;
  // Fixed regions: 130 MiB total
  unsigned short* buf0 = (unsigned short*)(ws);             // 64 MiB: h -> attno -> h2
  unsigned short* x2   = (unsigned short*)(ws + 64 * MB);   // 64 MiB: bf16 residual-1 output
  unsigned short* wqkv = (unsigned short*)(ws + 128 * MB);  // [768][256] bf16
  unsigned short* wmrg = wqkv + 768 * 256;                  // [256][256]
  unsigned short* w1t  = wmrg + 256 * 256;                  // [1024][256]
  unsigned short* w2t  = w1t + 1024 * 256;                  // [256][1024]
  float* relb          = (float*)(w2t + 256 * 1024);        // [8][64][64] f32
  unsigned short* Cbuf = (unsigned short*)(ws + 130 * MB);  // adaptive scratch

  // Adaptive chunk sizes from ws_size (deterministic)
  size_t avail = ws_size > 130 * MB ? ws_size - 130 * MB : 0;
  int wc = 64;                                   // windows per qkv/attn chunk
  {
    const int cands[5] = {2048, 1024, 512, 256, 128};
    for (int i = 0; i < 5; i++)
      if ((size_t)cands[i] * 64 * 768 * 2 <= avail) { wc = cands[i]; break; }
  }
  int rc = 2048;                                 // rows per MLP chunk
  {
    const int cands[6] = {131072, 65536, 32768, 16384, 8192, 4096};
    for (int i = 0; i < 6; i++)
      if ((size_t)cands[i] * 1024 * 2 <= avail) { rc = cands[i]; break; }
  }

  cast_wt<256, 768><<<768, 256, 0, stream>>>(qkv_w, wqkv);
  cast_wt<256, 256><<<256, 256, 0, stream>>>(merge_w, wmrg);
  cast_wt<256, 1024><<<1024, 256, 0, stream>>>(mlp_w1, w1t);
  cast_wt<1024, 256><<<1024, 256, 0, stream>>>(mlp_w2, w2t);
  build_relb<<<128, 256, 0, stream>>>(bias_table, relb);

  part_ln1<<<32768, 256, 0, stream>>>(x, ln1_g, ln1_b, buf0);

  // QKV + attention, chunked over windows through Cbuf
  for (int w0 = 0; w0 < 2048; w0 += wc) {
    gemm_bt<EPI_QKV><<<dim3(wc * 64 / 128, 6), 256, 0, stream>>>(
        buf0 + (size_t)w0 * 64 * 256, wqkv, qkv_b, nullptr, Cbuf, 256, 768, 0);
    attn_k<<<dim3(wc, 8), 64, 0, stream>>>(Cbuf, relb, buf0 + (size_t)w0 * 64 * 256);
  }

  // merge projection + residual(x gather) -> x2 bf16
  gemm_bt<EPI_MERGE><<<dim3(1024, 2), 256, 0, stream>>>(
      buf0, wmrg, merge_b, x, x2, 256, 256, 0);

  ln2k<<<32768, 256, 0, stream>>>(x2, ln2_g, ln2_b, buf0);

  // MLP, chunked over rows through Cbuf
  for (long r0 = 0; r0 < 131072; r0 += rc) {
    gemm_bt<EPI_GELU><<<dim3(rc / 128, 8), 256, 0, stream>>>(
        buf0 + (size_t)r0 * 256, w1t, mlp_b1, nullptr, Cbuf, 256, 1024, 0);
    gemm_bt<EPI_OUT><<<dim3(rc / 128, 2), 256, 0, stream>>>(
        Cbuf, w2t, mlp_b2, x2, d_out, 1024, 256, r0);
  }
}

// Round 4
// 933.967 us; speedup vs baseline: 1.0332x; 1.0332x over previous
//
#include <hip/hip_runtime.h>

typedef __attribute__((ext_vector_type(8))) short short8;
typedef __attribute__((ext_vector_type(4))) float f32x4;
typedef __attribute__((ext_vector_type(4))) int int4v;
typedef __attribute__((ext_vector_type(4))) unsigned short ushort4v;

#define SCALE_F 0.0625f   // C^-0.5 = 256^-0.5
#define EPS_F 1e-5f

__device__ __forceinline__ float bf2f(unsigned short u) {
  unsigned int i = ((unsigned int)u) << 16;
  return __builtin_bit_cast(float, i);
}
__device__ __forceinline__ unsigned short f2bf(float f) {
  unsigned int i = __builtin_bit_cast(unsigned int, f);
  i += 0x7fffu + ((i >> 16) & 1u);
  return (unsigned short)(i >> 16);
}

__device__ __forceinline__ void gload_lds16(const unsigned short* g, unsigned short* l) {
  __builtin_amdgcn_global_load_lds(
      (const __attribute__((address_space(1))) void*)g,
      (__attribute__((address_space(3))) void*)l, 16, 0, 0);
}

// ---- cast weight [K,N] f32 -> [N,K] bf16 (transposed) ----
template<int K, int N>
__global__ void cast_wt(const float* __restrict__ src, unsigned short* __restrict__ dst) {
  int id = blockIdx.x * 256 + threadIdx.x;          // id = n*K + k
  if (id >= K * N) return;
  int k = id % K, n = id / K;
  dst[id] = f2bf(src[(size_t)k * N + n]);
}

// ---- precompute relative-position bias [head][i][j] ----
__global__ void build_relb(const float* __restrict__ table, float* __restrict__ relb) {
  int id = blockIdx.x * 256 + threadIdx.x;          // 8*64*64
  int h = id >> 12, i = (id >> 6) & 63, j = id & 63;
  int dy = (i >> 3) - (j >> 3) + 7;
  int dx = (i & 7) - (j & 7) + 7;
  relb[id] = table[(dy * 15 + dx) * 8 + h];
}

// ---- window partition + LN1: x[B,C,64,64] -> h bf16 [M,256] ----
__global__ __launch_bounds__(256) void part_ln1(
    const float* __restrict__ x, const float* __restrict__ g, const float* __restrict__ bb,
    unsigned short* __restrict__ h) {
  int m = blockIdx.x * 4 + (threadIdx.x >> 6);
  int l = threadIdx.x & 63;
  int b = m >> 12, gg = (m >> 6) & 63, s = m & 63;
  int sp = ((gg >> 3) * 8 + (s >> 3)) * 64 + (gg & 7) * 8 + (s & 7);
  const float* xp = x + (size_t)b * 256 * 4096 + sp;
  float v[4];
  float sum = 0.f, ss = 0.f;
#pragma unroll
  for (int j = 0; j < 4; j++) {
    v[j] = xp[(size_t)(l * 4 + j) * 4096];
    sum += v[j]; ss += v[j] * v[j];
  }
#pragma unroll
  for (int d = 1; d < 64; d <<= 1) {
    sum += __shfl_xor(sum, d, 64);
    ss  += __shfl_xor(ss, d, 64);
  }
  float mu = sum * (1.f / 256.f);
  float var = ss * (1.f / 256.f) - mu * mu;
  float rs = rsqrtf(var + EPS_F);
  ushort4v oh;
#pragma unroll
  for (int j = 0; j < 4; j++) {
    int c = l * 4 + j;
    oh[j] = f2bf((v[j] - mu) * rs * g[c] + bb[c]);
  }
  *(ushort4v*)(h + (size_t)m * 256 + l * 4) = oh;
}

// ---- LN2: x2 bf16 [M,256] -> h2 bf16 [M,256] ----
__global__ __launch_bounds__(256) void ln2k(
    const unsigned short* __restrict__ x2, const float* __restrict__ g, const float* __restrict__ bb,
    unsigned short* __restrict__ h2) {
  int m = blockIdx.x * 4 + (threadIdx.x >> 6);
  int l = threadIdx.x & 63;
  ushort4v u = *(const ushort4v*)(x2 + (size_t)m * 256 + l * 4);
  float v[4];
  float sum = 0.f, ss = 0.f;
#pragma unroll
  for (int j = 0; j < 4; j++) { v[j] = bf2f(u[j]); sum += v[j]; ss += v[j] * v[j]; }
#pragma unroll
  for (int d = 1; d < 64; d <<= 1) {
    sum += __shfl_xor(sum, d, 64);
    ss  += __shfl_xor(ss, d, 64);
  }
  float mu = sum * (1.f / 256.f);
  float var = ss * (1.f / 256.f) - mu * mu;
  float rs = rsqrtf(var + EPS_F);
  ushort4v oh;
#pragma unroll
  for (int j = 0; j < 4; j++) {
    int c = l * 4 + j;
    oh[j] = f2bf((v[j] - mu) * rs * g[c] + bb[c]);
  }
  *(ushort4v*)(h2 + (size_t)m * 256 + l * 4) = oh;
}

// ---- GEMM: A bf16 [rows,K] x Bt bf16 [N,K] -> out, 128x128 tile, 4 waves ----
// Double-buffered global_load_lds staging with counted vmcnt prefetch (T3/T4):
// issue stage(k+1), s_waitcnt vmcnt(8) (the 8 older loads = buf k), raw barriers.
enum { EPI_QKV = 0, EPI_MERGE = 1, EPI_GELU = 2, EPI_OUT = 3 };

template<int EPI>
__global__ __launch_bounds__(256) void gemm_bt(
    const unsigned short* __restrict__ A, const unsigned short* __restrict__ Bt,
    const float* __restrict__ bias, const void* __restrict__ res,
    void* __restrict__ out, int K, int N, long m_base) {
  __shared__ __align__(16) unsigned short As[2][128 * 64];
  __shared__ __align__(16) unsigned short Bs[2][128 * 64];
  const int tid = threadIdx.x;
  const int l15 = tid & 15, lhi = (tid & 63) >> 4;
  const int wid = tid >> 6, wm = wid >> 1, wn = wid & 1;
  const size_t m0 = (size_t)blockIdx.x * 128;
  const int n0 = blockIdx.y * 128;
  const int row_s = tid >> 3, kc8 = (tid & 7) * 8;   // staging coords

  auto stage = [&](int kb, int k0) {
#pragma unroll
    for (int i = 0; i < 4; i++) {
      int row = i * 32 + row_s;
      gload_lds16(A + (m0 + row) * (size_t)K + k0 + kc8, &As[kb][(i * 256 + tid) * 8]);
      gload_lds16(Bt + (size_t)(n0 + row) * (size_t)K + k0 + kc8, &Bs[kb][(i * 256 + tid) * 8]);
    }
  };

  f32x4 acc[4][4];
#pragma unroll
  for (int i = 0; i < 4; i++)
#pragma unroll
    for (int j = 0; j < 4; j++) acc[i][j] = (f32x4){0.f, 0.f, 0.f, 0.f};

  stage(0, 0);                       // prologue: 8 loads/thread in flight
  int kb = 0;
  for (int k0 = 0; k0 < K; k0 += 64, kb ^= 1) {
    if (k0 + 64 < K) {
      stage(kb ^ 1, k0 + 64);        // 16 in flight
      asm volatile("s_waitcnt vmcnt(8)" ::: "memory");   // oldest 8 (buf kb) done
    } else {
      asm volatile("s_waitcnt vmcnt(0)" ::: "memory");
    }
    __builtin_amdgcn_s_barrier();    // buf kb resident for all waves
#pragma unroll
    for (int ks = 0; ks < 2; ks++) {
      short8 af[4], bfr[4];
#pragma unroll
      for (int t = 0; t < 4; t++) {
        af[t]  = *(const short8*)(&As[kb][(wm * 64 + t * 16 + l15) * 64 + ks * 32 + lhi * 8]);
        bfr[t] = *(const short8*)(&Bs[kb][(wn * 64 + t * 16 + l15) * 64 + ks * 32 + lhi * 8]);
      }
#pragma unroll
      for (int mt = 0; mt < 4; mt++)
#pragma unroll
        for (int nt = 0; nt < 4; nt++)
          acc[mt][nt] = __builtin_amdgcn_mfma_f32_16x16x32_bf16(af[mt], bfr[nt], acc[mt][nt], 0, 0, 0);
    }
    __builtin_amdgcn_s_barrier();    // buf kb consumed; next stage may overwrite
  }

#pragma unroll
  for (int mt = 0; mt < 4; mt++) {
#pragma unroll
    for (int nt = 0; nt < 4; nt++) {
#pragma unroll
      for (int r = 0; r < 4; r++) {
        size_t gml = m0 + wm * 64 + mt * 16 + lhi * 4 + r;   // chunk-local row
        size_t gm = gml + (size_t)m_base;                     // global row
        int gn = n0 + wn * 64 + nt * 16 + l15;
        float v = acc[mt][nt][r] + bias[gn];
        if (EPI == EPI_QKV) {
          ((unsigned short*)out)[gml * (size_t)N + gn] = f2bf(v);
        } else if (EPI == EPI_MERGE) {
          int bi = (int)(gm >> 12), gg = (int)((gm >> 6) & 63), s = (int)(gm & 63);
          size_t sp = ((gg >> 3) * 8 + (s >> 3)) * 64 + (gg & 7) * 8 + (s & 7);
          v += ((const float*)res)[((size_t)(bi * 256 + gn)) * 4096 + sp];
          ((unsigned short*)out)[gm * 256 + gn] = f2bf(v);
        } else if (EPI == EPI_GELU) {
          float gl = 0.5f * v * (1.f + erff(v * 0.70710678118f));
          ((unsigned short*)out)[gml * (size_t)N + gn] = f2bf(gl);
        } else {  // EPI_OUT: + x2 residual, departition to [B,C,64,64] f32
          v += bf2f(((const unsigned short*)res)[gm * 256 + gn]);
          int bi = (int)(gm >> 12), gg = (int)((gm >> 6) & 63), s = (int)(gm & 63);
          size_t o = (size_t)(bi * 256 + gn) * 4096 +
                     ((gg >> 3) * 8 + (s >> 3)) * 64 + (gg & 7) * 8 + (s & 7);
          ((float*)out)[o] = v;
        }
      }
    }
  }
}

// ---- attention: one wave per (window, head) ----
__global__ __launch_bounds__(64) void attn_k(
    const unsigned short* __restrict__ qkv, const float* __restrict__ relb,
    unsigned short* __restrict__ o) {
  __shared__ __align__(16) unsigned short p_lds[64 * 72];
  __shared__ __align__(16) unsigned short vt_lds[32 * 72];
  const int l = threadIdx.x;
  const int l15 = l & 15, lhi = l >> 4;
  const int w = blockIdx.x, head = blockIdx.y;
  const unsigned short* base = qkv + (size_t)w * 64 * 768 + head * 32;

  short8 aq[4], bk[4];
#pragma unroll
  for (int t = 0; t < 4; t++) {
    aq[t] = *(const short8*)(base + (t * 16 + l15) * 768 + lhi * 8);
    bk[t] = *(const short8*)(base + 256 + (t * 16 + l15) * 768 + lhi * 8);
  }
  f32x4 s[4][4];
#pragma unroll
  for (int i = 0; i < 4; i++)
#pragma unroll
    for (int j = 0; j < 4; j++) s[i][j] = (f32x4){0.f, 0.f, 0.f, 0.f};
#pragma unroll
  for (int mt = 0; mt < 4; mt++)
#pragma unroll
    for (int nt = 0; nt < 4; nt++)
      s[mt][nt] = __builtin_amdgcn_mfma_f32_16x16x32_bf16(aq[mt], bk[nt], s[mt][nt], 0, 0, 0);

  const float* rb = relb + head * 4096;
  float rsum[4][4];
#pragma unroll
  for (int mt = 0; mt < 4; mt++) {
#pragma unroll
    for (int r = 0; r < 4; r++) {
      int row = mt * 16 + lhi * 4 + r;
      float vv[4];
      float vmax = -1e30f;
#pragma unroll
      for (int nt = 0; nt < 4; nt++) {
        int col = nt * 16 + l15;
        float v = s[mt][nt][r] * SCALE_F + rb[row * 64 + col];
        vv[nt] = v;
        vmax = fmaxf(vmax, v);
      }
#pragma unroll
      for (int d = 1; d < 16; d <<= 1) vmax = fmaxf(vmax, __shfl_xor(vmax, d, 64));
      float sum = 0.f;
#pragma unroll
      for (int nt = 0; nt < 4; nt++) {
        float p = __expf(vv[nt] - vmax);
        sum += p;
        p_lds[row * 72 + nt * 16 + l15] = f2bf(p);
      }
#pragma unroll
      for (int d = 1; d < 16; d <<= 1) sum += __shfl_xor(sum, d, 64);
      rsum[mt][r] = 1.f / sum;
    }
  }

  // stage v^T: vt[dh][token]
#pragma unroll
  for (int j = 0; j < 4; j++) {
    short8 vv = *(const short8*)(base + 512 + l * 768 + j * 8);
#pragma unroll
    for (int e = 0; e < 8; e++)
      vt_lds[(j * 8 + e) * 72 + l] = (unsigned short)vv[e];
  }
  __syncthreads();

  f32x4 o2[4][2];
#pragma unroll
  for (int i = 0; i < 4; i++) { o2[i][0] = (f32x4){0.f,0.f,0.f,0.f}; o2[i][1] = (f32x4){0.f,0.f,0.f,0.f}; }
#pragma unroll
  for (int ks = 0; ks < 2; ks++) {
    short8 ap[4], bv[2];
#pragma unroll
    for (int t = 0; t < 4; t++)
      ap[t] = *(const short8*)(&p_lds[(t * 16 + l15) * 72 + ks * 32 + lhi * 8]);
#pragma unroll
    for (int t = 0; t < 2; t++)
      bv[t] = *(const short8*)(&vt_lds[(t * 16 + l15) * 72 + ks * 32 + lhi * 8]);
#pragma unroll
    for (int mt = 0; mt < 4; mt++)
#pragma unroll
      for (int n2 = 0; n2 < 2; n2++)
        o2[mt][n2] = __builtin_amdgcn_mfma_f32_16x16x32_bf16(ap[mt], bv[n2], o2[mt][n2], 0, 0, 0);
  }
#pragma unroll
  for (int mt = 0; mt < 4; mt++)
#pragma unroll
    for (int n2 = 0; n2 < 2; n2++)
#pragma unroll
      for (int r = 0; r < 4; r++) {
        int row = mt * 16 + lhi * 4 + r;
        int dh = n2 * 16 + l15;
        o[((size_t)w * 64 + row) * 256 + head * 32 + dh] = f2bf(o2[mt][n2][r] * rsum[mt][r]);
      }
}

extern "C" void kernel_launch(void* const* d_in, const int* in_sizes, int n_in,
                              void* d_out, int out_size, void* d_ws, size_t ws_size,
                              hipStream_t stream) {
  (void)in_sizes; (void)n_in; (void)out_size;
  const float* x          = (const float*)d_in[0];
  const float* ln1_g      = (const float*)d_in[1];
  const float* ln1_b      = (const float*)d_in[2];
  const float* qkv_w      = (const float*)d_in[3];
  const float* qkv_b      = (const float*)d_in[4];
  const float* merge_w    = (const float*)d_in[5];
  const float* merge_b    = (const float*)d_in[6];
  const float* bias_table = (const float*)d_in[7];
  const float* ln2_g      = (const float*)d_in[8];
  const float* ln2_b      = (const float*)d_in[9];
  const float* mlp_w1     = (const float*)d_in[10];
  const float* mlp_b1     = (const float*)d_in[11];
  const float* mlp_w2     = (const float*)d_in[12];
  const float* mlp_b2     = (const float*)d_in[13];

  const size_t MB = 1024ull * 1024ull;
  char* ws = (char*)d_ws;
  // Fixed regions: 130 MiB total
  unsigned short* buf0 = (unsigned short*)(ws);             // 64 MiB: h -> attno -> h2
  unsigned short* x2   = (unsigned short*)(ws + 64 * MB);   // 64 MiB: bf16 residual-1 output
  unsigned short* wqkv = (unsigned short*)(ws + 128 * MB);  // [768][256] bf16
  unsigned short* wmrg = wqkv + 768 * 256;                  // [256][256]
  unsigned short* w1t  = wmrg + 256 * 256;                  // [1024][256]
  unsigned short* w2t  = w1t + 1024 * 256;                  // [256][1024]
  float* relb          = (float*)(w2t + 256 * 1024);        // [8][64][64] f32
  unsigned short* Cbuf = (unsigned short*)(ws + 130 * MB);  // adaptive scratch

  // Adaptive chunk sizes from ws_size (deterministic).
  // Caps (512 windows / 32768 rows) keep the qkv and MLP-hidden intermediates
  // L3-resident between producer and consumer launches.
  size_t avail = ws_size > 130 * MB ? ws_size - 130 * MB : 0;
  int wc = 64;                                   // windows per qkv/attn chunk
  {
    const int cands[3] = {512, 256, 128};
    for (int i = 0; i < 3; i++)
      if ((size_t)cands[i] * 64 * 768 * 2 <= avail) { wc = cands[i]; break; }
  }
  int rc = 2048;                                 // rows per MLP chunk
  {
    const int cands[4] = {32768, 16384, 8192, 4096};
    for (int i = 0; i < 4; i++)
      if ((size_t)cands[i] * 1024 * 2 <= avail) { rc = cands[i]; break; }
  }

  cast_wt<256, 768><<<768, 256, 0, stream>>>(qkv_w, wqkv);
  cast_wt<256, 256><<<256, 256, 0, stream>>>(merge_w, wmrg);
  cast_wt<256, 1024><<<1024, 256, 0, stream>>>(mlp_w1, w1t);
  cast_wt<1024, 256><<<1024, 256, 0, stream>>>(mlp_w2, w2t);
  build_relb<<<128, 256, 0, stream>>>(bias_table, relb);

  part_ln1<<<32768, 256, 0, stream>>>(x, ln1_g, ln1_b, buf0);

  // QKV + attention, chunked over windows through Cbuf
  for (int w0 = 0; w0 < 2048; w0 += wc) {
    gemm_bt<EPI_QKV><<<dim3(wc * 64 / 128, 6), 256, 0, stream>>>(
        buf0 + (size_t)w0 * 64 * 256, wqkv, qkv_b, nullptr, Cbuf, 256, 768, 0);
    attn_k<<<dim3(wc, 8), 64, 0, stream>>>(Cbuf, relb, buf0 + (size_t)w0 * 64 * 256);
  }

  // merge projection + residual(x gather) -> x2 bf16
  gemm_bt<EPI_MERGE><<<dim3(1024, 2), 256, 0, stream>>>(
      buf0, wmrg, merge_b, x, x2, 256, 256, 0);

  ln2k<<<32768, 256, 0, stream>>>(x2, ln2_g, ln2_b, buf0);

  // MLP, chunked over rows through Cbuf
  for (long r0 = 0; r0 < 131072; r0 += rc) {
    gemm_bt<EPI_GELU><<<dim3(rc / 128, 8), 256, 0, stream>>>(
        buf0 + (size_t)r0 * 256, w1t, mlp_b1, nullptr, Cbuf, 256, 1024, 0);
    gemm_bt<EPI_OUT><<<dim3(rc / 128, 2), 256, 0, stream>>>(
        Cbuf, w2t, mlp_b2, x2, d_out, 1024, 256, r0);
  }
}

// Round 5
// 868.709 us; speedup vs baseline: 1.1108x; 1.0751x over previous
//
#include <hip/hip_runtime.h>

typedef __attribute__((ext_vector_type(8))) short short8;
typedef __attribute__((ext_vector_type(8))) unsigned short ushort8v;
typedef __attribute__((ext_vector_type(4))) float f32x4;
typedef __attribute__((ext_vector_type(4))) int int4v;
typedef __attribute__((ext_vector_type(4))) unsigned short ushort4v;
typedef __attribute__((ext_vector_type(2))) unsigned short ushort2v;

#define SCALE_F 0.0625f   // C^-0.5 = 256^-0.5
#define EPS_F 1e-5f

__device__ __forceinline__ float bf2f(unsigned short u) {
  unsigned int i = ((unsigned int)u) << 16;
  return __builtin_bit_cast(float, i);
}
__device__ __forceinline__ unsigned short f2bf(float f) {
  unsigned int i = __builtin_bit_cast(unsigned int, f);
  i += 0x7fffu + ((i >> 16) & 1u);
  return (unsigned short)(i >> 16);
}

__device__ __forceinline__ void gload_lds16(const unsigned short* g, unsigned short* l) {
  __builtin_amdgcn_global_load_lds(
      (const __attribute__((address_space(1))) void*)g,
      (__attribute__((address_space(3))) void*)l, 16, 0, 0);
}

// ---- cast weight [K,N] f32 -> [N,K] bf16 (transposed) ----
template<int K, int N>
__global__ void cast_wt(const float* __restrict__ src, unsigned short* __restrict__ dst) {
  int id = blockIdx.x * 256 + threadIdx.x;          // id = n*K + k
  if (id >= K * N) return;
  int k = id % K, n = id / K;
  dst[id] = f2bf(src[(size_t)k * N + n]);
}

// ---- precompute relative-position bias [head][i][j] ----
__global__ void build_relb(const float* __restrict__ table, float* __restrict__ relb) {
  int id = blockIdx.x * 256 + threadIdx.x;          // 8*64*64
  int h = id >> 12, i = (id >> 6) & 63, j = id & 63;
  int dy = (i >> 3) - (j >> 3) + 7;
  int dx = (i & 7) - (j & 7) + 7;
  relb[id] = table[(dy * 15 + dx) * 8 + h];
}

// ---- window partition + LN1 (coalesced transpose): x[B,C,64,64] -> h bf16 [M,256] ----
// Block covers 8 image rows x 16 cols (2 adjacent windows), all 256 channels.
#define PLN_RS 264   // LDS row stride in ushorts (256 + 8 pad)
__global__ __launch_bounds__(256) void part_ln1(
    const float* __restrict__ x, const float* __restrict__ g, const float* __restrict__ bb,
    unsigned short* __restrict__ h) {
  __shared__ __align__(16) unsigned short t_lds[128 * PLN_RS];
  __shared__ float ps_sum[128][2];
  __shared__ float ps_ss[128][2];
  const int tid = threadIdx.x;
  const int bid = blockIdx.x;
  const int b = bid >> 5, wr = (bid >> 2) & 7, cp = bid & 3;
  const int r0 = wr * 8;            // image row base
  const int c0 = cp * 16;           // image col base

  // Phase 1: coalesced read + transpose to LDS [px][ch]
  const int q = tid & 3, r = (tid >> 2) & 7, cb = tid >> 5;   // cb in 0..7
  const float* xb = x + (size_t)b * 256 * 4096 + (size_t)(r0 + r) * 64 + c0 + q * 4;
#pragma unroll
  for (int it = 0; it < 16; it++) {
    int cpair = it * 8 + cb;                 // channel pair 0..127
    const float* p0 = xb + (size_t)(2 * cpair) * 4096;
    f32x4 v0 = *(const f32x4*)p0;
    f32x4 v1 = *(const f32x4*)(p0 + 4096);
#pragma unroll
    for (int j = 0; j < 4; j++) {
      int px = r * 16 + q * 4 + j;
      ushort2v u = { f2bf(v0[j]), f2bf(v1[j]) };
      *(ushort2v*)(&t_lds[px * PLN_RS + 2 * cpair]) = u;
    }
  }
  __syncthreads();

  // Phase 2: per-pixel stats (2 threads per pixel)
  {
    const int p = tid & 127, half = tid >> 7;
    float sum = 0.f, ss = 0.f;
#pragma unroll
    for (int i = 0; i < 16; i++) {
      ushort8v u = *(const ushort8v*)(&t_lds[p * PLN_RS + half * 128 + i * 8]);
#pragma unroll
      for (int e = 0; e < 8; e++) { float f = bf2f(u[e]); sum += f; ss += f * f; }
    }
    ps_sum[p][half] = sum;
    ps_ss[p][half] = ss;
  }
  __syncthreads();

  // Phase 3: normalize + coalesced write (each row = 32 chunks of 16B)
#pragma unroll
  for (int w = 0; w < 16; w++) {
    int id = w * 256 + tid;
    int p = id >> 5, ch = id & 31;
    float mu = (ps_sum[p][0] + ps_sum[p][1]) * (1.f / 256.f);
    float var = (ps_ss[p][0] + ps_ss[p][1]) * (1.f / 256.f) - mu * mu;
    float rs = rsqrtf(var + EPS_F);
    ushort8v u = *(const ushort8v*)(&t_lds[p * PLN_RS + ch * 8]);
    f32x4 g0 = *(const f32x4*)(g + ch * 8);
    f32x4 g1 = *(const f32x4*)(g + ch * 8 + 4);
    f32x4 b0 = *(const f32x4*)(bb + ch * 8);
    f32x4 b1 = *(const f32x4*)(bb + ch * 8 + 4);
    ushort8v o;
#pragma unroll
    for (int e = 0; e < 4; e++) {
      o[e]     = f2bf((bf2f(u[e])     - mu) * rs * g0[e] + b0[e]);
      o[e + 4] = f2bf((bf2f(u[e + 4]) - mu) * rs * g1[e] + b1[e]);
    }
    int rr = p >> 4, col = p & 15;
    size_t m = (size_t)b * 4096 + (size_t)(wr * 8 + cp * 2 + (col >> 3)) * 64 + rr * 8 + (col & 7);
    *(ushort8v*)(h + m * 256 + ch * 8) = o;
  }
}

// ---- LN2: x2 bf16 [M,256] -> h2 bf16 [M,256] ----
__global__ __launch_bounds__(256) void ln2k(
    const unsigned short* __restrict__ x2, const float* __restrict__ g, const float* __restrict__ bb,
    unsigned short* __restrict__ h2) {
  int m = blockIdx.x * 4 + (threadIdx.x >> 6);
  int l = threadIdx.x & 63;
  ushort4v u = *(const ushort4v*)(x2 + (size_t)m * 256 + l * 4);
  float v[4];
  float sum = 0.f, ss = 0.f;
#pragma unroll
  for (int j = 0; j < 4; j++) { v[j] = bf2f(u[j]); sum += v[j]; ss += v[j] * v[j]; }
#pragma unroll
  for (int d = 1; d < 64; d <<= 1) {
    sum += __shfl_xor(sum, d, 64);
    ss  += __shfl_xor(ss, d, 64);
  }
  float mu = sum * (1.f / 256.f);
  float var = ss * (1.f / 256.f) - mu * mu;
  float rs = rsqrtf(var + EPS_F);
  ushort4v oh;
#pragma unroll
  for (int j = 0; j < 4; j++) {
    int c = l * 4 + j;
    oh[j] = f2bf((v[j] - mu) * rs * g[c] + bb[c]);
  }
  *(ushort4v*)(h2 + (size_t)m * 256 + l * 4) = oh;
}

// ---- GEMM: A bf16 [rows,K] x Bt bf16 [N,K] -> out, 128x128 tile, 4 waves ----
// Double-buffered global_load_lds staging with counted vmcnt prefetch (T3/T4).
enum { EPI_QKV = 0, EPI_MERGE = 1, EPI_GELU = 2, EPI_OUT = 3 };

template<int EPI>
__device__ __forceinline__ void gemm_body(
    unsigned short* As, unsigned short* Bs,
    const unsigned short* __restrict__ A, const unsigned short* __restrict__ Bt,
    const float* __restrict__ bias, const void* __restrict__ res,
    void* __restrict__ out, int K, int N, long m_base) {
  const int tid = threadIdx.x;
  const int l15 = tid & 15, lhi = (tid & 63) >> 4;
  const int wid = tid >> 6, wm = wid >> 1, wn = wid & 1;
  const size_t m0 = (size_t)blockIdx.x * 128;
  const int n0 = blockIdx.y * 128;
  const int row_s = tid >> 3, kc8 = (tid & 7) * 8;   // staging coords

  auto stage = [&](int kb, int k0) {
#pragma unroll
    for (int i = 0; i < 4; i++) {
      int row = i * 32 + row_s;
      gload_lds16(A + (m0 + row) * (size_t)K + k0 + kc8, &As[kb * 8192 + (i * 256 + tid) * 8]);
      gload_lds16(Bt + (size_t)(n0 + row) * (size_t)K + k0 + kc8, &Bs[kb * 8192 + (i * 256 + tid) * 8]);
    }
  };

  f32x4 acc[4][4];
#pragma unroll
  for (int i = 0; i < 4; i++)
#pragma unroll
    for (int j = 0; j < 4; j++) acc[i][j] = (f32x4){0.f, 0.f, 0.f, 0.f};

  stage(0, 0);                       // prologue: 8 loads/thread in flight
  int kb = 0;
  for (int k0 = 0; k0 < K; k0 += 64, kb ^= 1) {
    if (k0 + 64 < K) {
      stage(kb ^ 1, k0 + 64);        // 16 in flight
      asm volatile("s_waitcnt vmcnt(8)" ::: "memory");   // oldest 8 (buf kb) done
    } else {
      asm volatile("s_waitcnt vmcnt(0)" ::: "memory");
    }
    __builtin_amdgcn_s_barrier();    // buf kb resident for all waves
#pragma unroll
    for (int ks = 0; ks < 2; ks++) {
      short8 af[4], bfr[4];
#pragma unroll
      for (int t = 0; t < 4; t++) {
        af[t]  = *(const short8*)(&As[kb * 8192 + (wm * 64 + t * 16 + l15) * 64 + ks * 32 + lhi * 8]);
        bfr[t] = *(const short8*)(&Bs[kb * 8192 + (wn * 64 + t * 16 + l15) * 64 + ks * 32 + lhi * 8]);
      }
#pragma unroll
      for (int mt = 0; mt < 4; mt++)
#pragma unroll
        for (int nt = 0; nt < 4; nt++)
          acc[mt][nt] = __builtin_amdgcn_mfma_f32_16x16x32_bf16(af[mt], bfr[nt], acc[mt][nt], 0, 0, 0);
    }
    __builtin_amdgcn_s_barrier();    // buf kb consumed; next stage may overwrite
  }

#pragma unroll
  for (int mt = 0; mt < 4; mt++) {
#pragma unroll
    for (int nt = 0; nt < 4; nt++) {
#pragma unroll
      for (int r = 0; r < 4; r++) {
        size_t gml = m0 + wm * 64 + mt * 16 + lhi * 4 + r;   // chunk-local row
        size_t gm = gml + (size_t)m_base;                     // global row
        int gn = n0 + wn * 64 + nt * 16 + l15;
        float v = acc[mt][nt][r] + bias[gn];
        if (EPI == EPI_QKV) {
          ((unsigned short*)out)[gml * (size_t)N + gn] = f2bf(v);
        } else if (EPI == EPI_MERGE) {
          int bi = (int)(gm >> 12), gg = (int)((gm >> 6) & 63), s = (int)(gm & 63);
          size_t sp = ((gg >> 3) * 8 + (s >> 3)) * 64 + (gg & 7) * 8 + (s & 7);
          v += ((const float*)res)[((size_t)(bi * 256 + gn)) * 4096 + sp];
          ((unsigned short*)out)[gm * 256 + gn] = f2bf(v);
        } else if (EPI == EPI_GELU) {
          float gl = 0.5f * v * (1.f + erff(v * 0.70710678118f));
          ((unsigned short*)out)[gml * (size_t)N + gn] = f2bf(gl);
        } else {  // EPI_OUT: + x2 residual, departition to [B,C,64,64] f32
          v += bf2f(((const unsigned short*)res)[gm * 256 + gn]);
          int bi = (int)(gm >> 12), gg = (int)((gm >> 6) & 63), s = (int)(gm & 63);
          size_t o = (size_t)(bi * 256 + gn) * 4096 +
                     ((gg >> 3) * 8 + (s >> 3)) * 64 + (gg & 7) * 8 + (s & 7);
          ((float*)out)[o] = v;
        }
      }
    }
  }
}

#define GEMM_WRAP(name, epi)                                                          \
__global__ __launch_bounds__(256) void name(                                          \
    const unsigned short* __restrict__ A, const unsigned short* __restrict__ Bt,      \
    const float* __restrict__ bias, const void* __restrict__ res,                     \
    void* __restrict__ out, int K, int N, long m_base) {                              \
  __shared__ __align__(16) unsigned short As[2 * 128 * 64];                           \
  __shared__ __align__(16) unsigned short Bs[2 * 128 * 64];                           \
  gemm_body<epi>(As, Bs, A, Bt, bias, res, out, K, N, m_base);                        \
}
GEMM_WRAP(gemm_qkv, EPI_QKV)
GEMM_WRAP(gemm_merge, EPI_MERGE)
GEMM_WRAP(gemm_gelu, EPI_GELU)
GEMM_WRAP(gemm_out, EPI_OUT)

// ---- attention: one wave per (window, head) ----
__global__ __launch_bounds__(64) void attn_k(
    const unsigned short* __restrict__ qkv, const float* __restrict__ relb,
    unsigned short* __restrict__ o) {
  __shared__ __align__(16) unsigned short p_lds[64 * 72];
  __shared__ __align__(16) unsigned short vt_lds[32 * 72];
  const int l = threadIdx.x;
  const int l15 = l & 15, lhi = l >> 4;
  const int w = blockIdx.x, head = blockIdx.y;
  const unsigned short* base = qkv + (size_t)w * 64 * 768 + head * 32;

  short8 aq[4], bk[4];
#pragma unroll
  for (int t = 0; t < 4; t++) {
    aq[t] = *(const short8*)(base + (t * 16 + l15) * 768 + lhi * 8);
    bk[t] = *(const short8*)(base + 256 + (t * 16 + l15) * 768 + lhi * 8);
  }
  f32x4 s[4][4];
#pragma unroll
  for (int i = 0; i < 4; i++)
#pragma unroll
    for (int j = 0; j < 4; j++) s[i][j] = (f32x4){0.f, 0.f, 0.f, 0.f};
#pragma unroll
  for (int mt = 0; mt < 4; mt++)
#pragma unroll
    for (int nt = 0; nt < 4; nt++)
      s[mt][nt] = __builtin_amdgcn_mfma_f32_16x16x32_bf16(aq[mt], bk[nt], s[mt][nt], 0, 0, 0);

  const float* rb = relb + head * 4096;
  float rsum[4][4];
#pragma unroll
  for (int mt = 0; mt < 4; mt++) {
#pragma unroll
    for (int r = 0; r < 4; r++) {
      int row = mt * 16 + lhi * 4 + r;
      float vv[4];
      float vmax = -1e30f;
#pragma unroll
      for (int nt = 0; nt < 4; nt++) {
        int col = nt * 16 + l15;
        float v = s[mt][nt][r] * SCALE_F + rb[row * 64 + col];
        vv[nt] = v;
        vmax = fmaxf(vmax, v);
      }
#pragma unroll
      for (int d = 1; d < 16; d <<= 1) vmax = fmaxf(vmax, __shfl_xor(vmax, d, 64));
      float sum = 0.f;
#pragma unroll
      for (int nt = 0; nt < 4; nt++) {
        float p = __expf(vv[nt] - vmax);
        sum += p;
        p_lds[row * 72 + nt * 16 + l15] = f2bf(p);
      }
#pragma unroll
      for (int d = 1; d < 16; d <<= 1) sum += __shfl_xor(sum, d, 64);
      rsum[mt][r] = 1.f / sum;
    }
  }

  // stage v^T: vt[dh][token]
#pragma unroll
  for (int j = 0; j < 4; j++) {
    short8 vv = *(const short8*)(base + 512 + l * 768 + j * 8);
#pragma unroll
    for (int e = 0; e < 8; e++)
      vt_lds[(j * 8 + e) * 72 + l] = (unsigned short)vv[e];
  }
  __syncthreads();

  f32x4 o2[4][2];
#pragma unroll
  for (int i = 0; i < 4; i++) { o2[i][0] = (f32x4){0.f,0.f,0.f,0.f}; o2[i][1] = (f32x4){0.f,0.f,0.f,0.f}; }
#pragma unroll
  for (int ks = 0; ks < 2; ks++) {
    short8 ap[4], bv[2];
#pragma unroll
    for (int t = 0; t < 4; t++)
      ap[t] = *(const short8*)(&p_lds[(t * 16 + l15) * 72 + ks * 32 + lhi * 8]);
#pragma unroll
    for (int t = 0; t < 2; t++)
      bv[t] = *(const short8*)(&vt_lds[(t * 16 + l15) * 72 + ks * 32 + lhi * 8]);
#pragma unroll
    for (int mt = 0; mt < 4; mt++)
#pragma unroll
      for (int n2 = 0; n2 < 2; n2++)
        o2[mt][n2] = __builtin_amdgcn_mfma_f32_16x16x32_bf16(ap[mt], bv[n2], o2[mt][n2], 0, 0, 0);
  }
#pragma unroll
  for (int mt = 0; mt < 4; mt++)
#pragma unroll
    for (int n2 = 0; n2 < 2; n2++)
#pragma unroll
      for (int r = 0; r < 4; r++) {
        int row = mt * 16 + lhi * 4 + r;
        int dh = n2 * 16 + l15;
        o[((size_t)w * 64 + row) * 256 + head * 32 + dh] = f2bf(o2[mt][n2][r] * rsum[mt][r]);
      }
}

extern "C" void kernel_launch(void* const* d_in, const int* in_sizes, int n_in,
                              void* d_out, int out_size, void* d_ws, size_t ws_size,
                              hipStream_t stream) {
  (void)in_sizes; (void)n_in; (void)out_size;
  const float* x          = (const float*)d_in[0];
  const float* ln1_g      = (const float*)d_in[1];
  const float* ln1_b      = (const float*)d_in[2];
  const float* qkv_w      = (const float*)d_in[3];
  const float* qkv_b      = (const float*)d_in[4];
  const float* merge_w    = (const float*)d_in[5];
  const float* merge_b    = (const float*)d_in[6];
  const float* bias_table = (const float*)d_in[7];
  const float* ln2_g      = (const float*)d_in[8];
  const float* ln2_b      = (const float*)d_in[9];
  const float* mlp_w1     = (const float*)d_in[10];
  const float* mlp_b1     = (const float*)d_in[11];
  const float* mlp_w2     = (const float*)d_in[12];
  const float* mlp_b2     = (const float*)d_in[13];

  const size_t MB = 1024ull * 1024ull;
  char* ws = (char*)d_ws;
  // Fixed regions: 130 MiB total
  unsigned short* buf0 = (unsigned short*)(ws);             // 64 MiB: h -> attno -> h2
  unsigned short* x2   = (unsigned short*)(ws + 64 * MB);   // 64 MiB: bf16 residual-1 output
  unsigned short* wqkv = (unsigned short*)(ws + 128 * MB);  // [768][256] bf16
  unsigned short* wmrg = wqkv + 768 * 256;                  // [256][256]
  unsigned short* w1t  = wmrg + 256 * 256;                  // [1024][256]
  unsigned short* w2t  = w1t + 1024 * 256;                  // [256][1024]
  float* relb          = (float*)(w2t + 256 * 1024);        // [8][64][64] f32
  unsigned short* Cbuf = (unsigned short*)(ws + 130 * MB);  // adaptive scratch

  // Adaptive chunk sizes from ws_size (deterministic).
  size_t avail = ws_size > 130 * MB ? ws_size - 130 * MB : 0;
  int wc = 64;                                   // windows per qkv/attn chunk
  {
    const int cands[3] = {512, 256, 128};
    for (int i = 0; i < 3; i++)
      if ((size_t)cands[i] * 64 * 768 * 2 <= avail) { wc = cands[i]; break; }
  }
  int rc = 2048;                                 // rows per MLP chunk
  {
    const int cands[4] = {32768, 16384, 8192, 4096};
    for (int i = 0; i < 4; i++)
      if ((size_t)cands[i] * 1024 * 2 <= avail) { rc = cands[i]; break; }
  }

  cast_wt<256, 768><<<768, 256, 0, stream>>>(qkv_w, wqkv);
  cast_wt<256, 256><<<256, 256, 0, stream>>>(merge_w, wmrg);
  cast_wt<256, 1024><<<1024, 256, 0, stream>>>(mlp_w1, w1t);
  cast_wt<1024, 256><<<1024, 256, 0, stream>>>(mlp_w2, w2t);
  build_relb<<<128, 256, 0, stream>>>(bias_table, relb);

  part_ln1<<<1024, 256, 0, stream>>>(x, ln1_g, ln1_b, buf0);

  // QKV + attention, chunked over windows through Cbuf
  for (int w0 = 0; w0 < 2048; w0 += wc) {
    gemm_qkv<<<dim3(wc * 64 / 128, 6), 256, 0, stream>>>(
        buf0 + (size_t)w0 * 64 * 256, wqkv, qkv_b, nullptr, Cbuf, 256, 768, 0);
    attn_k<<<dim3(wc, 8), 64, 0, stream>>>(Cbuf, relb, buf0 + (size_t)w0 * 64 * 256);
  }

  // merge projection + residual(x gather) -> x2 bf16
  gemm_merge<<<dim3(1024, 2), 256, 0, stream>>>(
      buf0, wmrg, merge_b, x, x2, 256, 256, 0);

  ln2k<<<32768, 256, 0, stream>>>(x2, ln2_g, ln2_b, buf0);

  // MLP, chunked over rows through Cbuf
  for (long r0 = 0; r0 < 131072; r0 += rc) {
    gemm_gelu<<<dim3(rc / 128, 8), 256, 0, stream>>>(
        buf0 + (size_t)r0 * 256, w1t, mlp_b1, nullptr, Cbuf, 256, 1024, 0);
    gemm_out<<<dim3(rc / 128, 2), 256, 0, stream>>>(
        Cbuf, w2t, mlp_b2, x2, d_out, 1024, 256, r0);
  }
}

// Round 6
// 777.318 us; speedup vs baseline: 1.2415x; 1.1176x over previous
//
#include <hip/hip_runtime.h>

typedef __attribute__((ext_vector_type(8))) short short8;
typedef __attribute__((ext_vector_type(8))) unsigned short ushort8v;
typedef __attribute__((ext_vector_type(4))) float f32x4;
typedef __attribute__((ext_vector_type(4))) int int4v;
typedef __attribute__((ext_vector_type(4))) unsigned short ushort4v;
typedef __attribute__((ext_vector_type(2))) unsigned short ushort2v;

#define SCALE_F 0.0625f   // C^-0.5 = 256^-0.5
#define EPS_F 1e-5f

__device__ __forceinline__ float bf2f(unsigned short u) {
  unsigned int i = ((unsigned int)u) << 16;
  return __builtin_bit_cast(float, i);
}
__device__ __forceinline__ unsigned short f2bf(float f) {
  unsigned int i = __builtin_bit_cast(unsigned int, f);
  i += 0x7fffu + ((i >> 16) & 1u);
  return (unsigned short)(i >> 16);
}

__device__ __forceinline__ void gload_lds16(const unsigned short* g, unsigned short* l) {
  __builtin_amdgcn_global_load_lds(
      (const __attribute__((address_space(1))) void*)g,
      (__attribute__((address_space(3))) void*)l, 16, 0, 0);
}

// ---- cast weight [K,N] f32 -> [N,K] bf16 (transposed) ----
template<int K, int N>
__global__ void cast_wt(const float* __restrict__ src, unsigned short* __restrict__ dst) {
  int id = blockIdx.x * 256 + threadIdx.x;          // id = n*K + k
  if (id >= K * N) return;
  int k = id % K, n = id / K;
  dst[id] = f2bf(src[(size_t)k * N + n]);
}

// ---- precompute relative-position bias [head][i][j] ----
__global__ void build_relb(const float* __restrict__ table, float* __restrict__ relb) {
  int id = blockIdx.x * 256 + threadIdx.x;          // 8*64*64
  int h = id >> 12, i = (id >> 6) & 63, j = id & 63;
  int dy = (i >> 3) - (j >> 3) + 7;
  int dx = (i & 7) - (j & 7) + 7;
  relb[id] = table[(dy * 15 + dx) * 8 + h];
}

// ---- window partition + LN1 (coalesced transpose): x[B,C,64,64] -> h bf16 [M,256] ----
#define PLN_RS 264   // LDS row stride in ushorts (256 + 8 pad)
__global__ __launch_bounds__(256) void part_ln1(
    const float* __restrict__ x, const float* __restrict__ g, const float* __restrict__ bb,
    unsigned short* __restrict__ h) {
  __shared__ __align__(16) unsigned short t_lds[128 * PLN_RS];
  __shared__ float ps_sum[128][2];
  __shared__ float ps_ss[128][2];
  const int tid = threadIdx.x;
  const int bid = blockIdx.x;
  const int b = bid >> 5, wr = (bid >> 2) & 7, cp = bid & 3;
  const int r0 = wr * 8;            // image row base
  const int c0 = cp * 16;           // image col base

  // Phase 1: coalesced read + transpose to LDS [px][ch]
  const int q = tid & 3, r = (tid >> 2) & 7, cb = tid >> 5;   // cb in 0..7
  const float* xb = x + (size_t)b * 256 * 4096 + (size_t)(r0 + r) * 64 + c0 + q * 4;
#pragma unroll
  for (int it = 0; it < 16; it++) {
    int cpair = it * 8 + cb;                 // channel pair 0..127
    const float* p0 = xb + (size_t)(2 * cpair) * 4096;
    f32x4 v0 = *(const f32x4*)p0;
    f32x4 v1 = *(const f32x4*)(p0 + 4096);
#pragma unroll
    for (int j = 0; j < 4; j++) {
      int px = r * 16 + q * 4 + j;
      ushort2v u = { f2bf(v0[j]), f2bf(v1[j]) };
      *(ushort2v*)(&t_lds[px * PLN_RS + 2 * cpair]) = u;
    }
  }
  __syncthreads();

  // Phase 2: per-pixel stats (2 threads per pixel)
  {
    const int p = tid & 127, half = tid >> 7;
    float sum = 0.f, ss = 0.f;
#pragma unroll
    for (int i = 0; i < 16; i++) {
      ushort8v u = *(const ushort8v*)(&t_lds[p * PLN_RS + half * 128 + i * 8]);
#pragma unroll
      for (int e = 0; e < 8; e++) { float f = bf2f(u[e]); sum += f; ss += f * f; }
    }
    ps_sum[p][half] = sum;
    ps_ss[p][half] = ss;
  }
  __syncthreads();

  // Phase 3: normalize + coalesced write (each row = 32 chunks of 16B)
#pragma unroll
  for (int w = 0; w < 16; w++) {
    int id = w * 256 + tid;
    int p = id >> 5, ch = id & 31;
    float mu = (ps_sum[p][0] + ps_sum[p][1]) * (1.f / 256.f);
    float var = (ps_ss[p][0] + ps_ss[p][1]) * (1.f / 256.f) - mu * mu;
    float rs = rsqrtf(var + EPS_F);
    ushort8v u = *(const ushort8v*)(&t_lds[p * PLN_RS + ch * 8]);
    f32x4 g0 = *(const f32x4*)(g + ch * 8);
    f32x4 g1 = *(const f32x4*)(g + ch * 8 + 4);
    f32x4 b0 = *(const f32x4*)(bb + ch * 8);
    f32x4 b1 = *(const f32x4*)(bb + ch * 8 + 4);
    ushort8v o;
#pragma unroll
    for (int e = 0; e < 4; e++) {
      o[e]     = f2bf((bf2f(u[e])     - mu) * rs * g0[e] + b0[e]);
      o[e + 4] = f2bf((bf2f(u[e + 4]) - mu) * rs * g1[e] + b1[e]);
    }
    int rr = p >> 4, col = p & 15;
    size_t m = (size_t)b * 4096 + (size_t)(wr * 8 + cp * 2 + (col >> 3)) * 64 + rr * 8 + (col & 7);
    *(ushort8v*)(h + m * 256 + ch * 8) = o;
  }
}

// ---- LN2: x2 bf16 [M,256] -> h2 bf16 [M,256] ----
__global__ __launch_bounds__(256) void ln2k(
    const unsigned short* __restrict__ x2, const float* __restrict__ g, const float* __restrict__ bb,
    unsigned short* __restrict__ h2) {
  int m = blockIdx.x * 4 + (threadIdx.x >> 6);
  int l = threadIdx.x & 63;
  ushort4v u = *(const ushort4v*)(x2 + (size_t)m * 256 + l * 4);
  float v[4];
  float sum = 0.f, ss = 0.f;
#pragma unroll
  for (int j = 0; j < 4; j++) { v[j] = bf2f(u[j]); sum += v[j]; ss += v[j] * v[j]; }
#pragma unroll
  for (int d = 1; d < 64; d <<= 1) {
    sum += __shfl_xor(sum, d, 64);
    ss  += __shfl_xor(ss, d, 64);
  }
  float mu = sum * (1.f / 256.f);
  float var = ss * (1.f / 256.f) - mu * mu;
  float rs = rsqrtf(var + EPS_F);
  ushort4v oh;
#pragma unroll
  for (int j = 0; j < 4; j++) {
    int c = l * 4 + j;
    oh[j] = f2bf((v[j] - mu) * rs * g[c] + bb[c]);
  }
  *(ushort4v*)(h2 + (size_t)m * 256 + l * 4) = oh;
}

// ---- GEMM: A bf16 [rows,K] x Bt bf16 [N,K] -> out, 128x128 tile, 4 waves ----
// Double-buffered global_load_lds staging with counted vmcnt prefetch (T3/T4).
// Epilogues: vectorized f32x4 residual-gather (MERGE) and f32x4 scatter-store (OUT):
// within a fragment, r=0..3 are 4 consecutive pixels of one image row.
enum { EPI_QKV = 0, EPI_MERGE = 1, EPI_GELU = 2, EPI_OUT = 3 };

template<int EPI>
__device__ __forceinline__ void gemm_body(
    unsigned short* As, unsigned short* Bs,
    const unsigned short* __restrict__ A, const unsigned short* __restrict__ Bt,
    const float* __restrict__ bias, const void* __restrict__ res,
    void* __restrict__ out, int K, int N, long m_base) {
  const int tid = threadIdx.x;
  const int l15 = tid & 15, lhi = (tid & 63) >> 4;
  const int wid = tid >> 6, wm = wid >> 1, wn = wid & 1;
  const size_t m0 = (size_t)blockIdx.x * 128;
  const int n0 = blockIdx.y * 128;
  const int row_s = tid >> 3, kc8 = (tid & 7) * 8;   // staging coords

  auto stage = [&](int kb, int k0) {
#pragma unroll
    for (int i = 0; i < 4; i++) {
      int row = i * 32 + row_s;
      gload_lds16(A + (m0 + row) * (size_t)K + k0 + kc8, &As[kb * 8192 + (i * 256 + tid) * 8]);
      gload_lds16(Bt + (size_t)(n0 + row) * (size_t)K + k0 + kc8, &Bs[kb * 8192 + (i * 256 + tid) * 8]);
    }
  };

  f32x4 acc[4][4];
#pragma unroll
  for (int i = 0; i < 4; i++)
#pragma unroll
    for (int j = 0; j < 4; j++) acc[i][j] = (f32x4){0.f, 0.f, 0.f, 0.f};

  stage(0, 0);                       // prologue: 8 loads/thread in flight
  int kb = 0;
  for (int k0 = 0; k0 < K; k0 += 64, kb ^= 1) {
    if (k0 + 64 < K) {
      stage(kb ^ 1, k0 + 64);        // 16 in flight
      asm volatile("s_waitcnt vmcnt(8)" ::: "memory");   // oldest 8 (buf kb) done
    } else {
      asm volatile("s_waitcnt vmcnt(0)" ::: "memory");
    }
    __builtin_amdgcn_s_barrier();    // buf kb resident for all waves
#pragma unroll
    for (int ks = 0; ks < 2; ks++) {
      short8 af[4], bfr[4];
#pragma unroll
      for (int t = 0; t < 4; t++) {
        af[t]  = *(const short8*)(&As[kb * 8192 + (wm * 64 + t * 16 + l15) * 64 + ks * 32 + lhi * 8]);
        bfr[t] = *(const short8*)(&Bs[kb * 8192 + (wn * 64 + t * 16 + l15) * 64 + ks * 32 + lhi * 8]);
      }
#pragma unroll
      for (int mt = 0; mt < 4; mt++)
#pragma unroll
        for (int nt = 0; nt < 4; nt++)
          acc[mt][nt] = __builtin_amdgcn_mfma_f32_16x16x32_bf16(af[mt], bfr[nt], acc[mt][nt], 0, 0, 0);
    }
    __builtin_amdgcn_s_barrier();    // buf kb consumed; next stage may overwrite
  }

#pragma unroll
  for (int mt = 0; mt < 4; mt++) {
#pragma unroll
    for (int nt = 0; nt < 4; nt++) {
      const size_t gml0 = m0 + wm * 64 + mt * 16 + lhi * 4;   // chunk-local row base (4 consecutive)
      const size_t gm0 = gml0 + (size_t)m_base;               // global row base
      const int gn = n0 + wn * 64 + nt * 16 + l15;
      if (EPI == EPI_QKV) {
#pragma unroll
        for (int r = 0; r < 4; r++)
          ((unsigned short*)out)[(gml0 + r) * (size_t)N + gn] = f2bf(acc[mt][nt][r] + bias[gn]);
      } else if (EPI == EPI_MERGE) {
        // r=0..3 are 4 consecutive pixels in one image row -> one f32x4 gather
        int bi = (int)(gm0 >> 12), gg = (int)((gm0 >> 6) & 63), s0 = (int)(gm0 & 63);
        size_t sp = (size_t)((gg >> 3) * 8 + (s0 >> 3)) * 64 + (gg & 7) * 8 + (s0 & 7);
        f32x4 xr = *(const f32x4*)(&((const float*)res)[((size_t)(bi * 256 + gn)) * 4096 + sp]);
#pragma unroll
        for (int r = 0; r < 4; r++)
          ((unsigned short*)out)[(gm0 + r) * 256 + gn] = f2bf(acc[mt][nt][r] + bias[gn] + xr[r]);
      } else if (EPI == EPI_GELU) {
#pragma unroll
        for (int r = 0; r < 4; r++) {
          float v = acc[mt][nt][r] + bias[gn];
          float gl = 0.5f * v * (1.f + erff(v * 0.70710678118f));
          ((unsigned short*)out)[(gml0 + r) * (size_t)N + gn] = f2bf(gl);
        }
      } else {  // EPI_OUT: + x2 residual, departition, one f32x4 store
        int bi = (int)(gm0 >> 12), gg = (int)((gm0 >> 6) & 63), s0 = (int)(gm0 & 63);
        size_t sp = (size_t)((gg >> 3) * 8 + (s0 >> 3)) * 64 + (gg & 7) * 8 + (s0 & 7);
        f32x4 o4;
#pragma unroll
        for (int r = 0; r < 4; r++)
          o4[r] = acc[mt][nt][r] + bias[gn] + bf2f(((const unsigned short*)res)[(gm0 + r) * 256 + gn]);
        *(f32x4*)(&((float*)out)[((size_t)(bi * 256 + gn)) * 4096 + sp]) = o4;
      }
    }
  }
}

#define GEMM_WRAP(name, epi)                                                          \
__global__ __launch_bounds__(256) void name(                                          \
    const unsigned short* __restrict__ A, const unsigned short* __restrict__ Bt,      \
    const float* __restrict__ bias, const void* __restrict__ res,                     \
    void* __restrict__ out, int K, int N, long m_base) {                              \
  __shared__ __align__(16) unsigned short As[2 * 128 * 64];                           \
  __shared__ __align__(16) unsigned short Bs[2 * 128 * 64];                           \
  gemm_body<epi>(As, Bs, A, Bt, bias, res, out, K, N, m_base);                        \
}
GEMM_WRAP(gemm_qkv, EPI_QKV)
GEMM_WRAP(gemm_merge, EPI_MERGE)
GEMM_WRAP(gemm_gelu, EPI_GELU)
GEMM_WRAP(gemm_out, EPI_OUT)

// ---- attention: one wave per (window, head) ----
__global__ __launch_bounds__(64) void attn_k(
    const unsigned short* __restrict__ qkv, const float* __restrict__ relb,
    unsigned short* __restrict__ o) {
  __shared__ __align__(16) unsigned short p_lds[64 * 72];
  __shared__ __align__(16) unsigned short vt_lds[32 * 72];
  const int l = threadIdx.x;
  const int l15 = l & 15, lhi = l >> 4;
  const int w = blockIdx.x, head = blockIdx.y;
  const unsigned short* base = qkv + (size_t)w * 64 * 768 + head * 32;

  short8 aq[4], bk[4];
#pragma unroll
  for (int t = 0; t < 4; t++) {
    aq[t] = *(const short8*)(base + (t * 16 + l15) * 768 + lhi * 8);
    bk[t] = *(const short8*)(base + 256 + (t * 16 + l15) * 768 + lhi * 8);
  }
  f32x4 s[4][4];
#pragma unroll
  for (int i = 0; i < 4; i++)
#pragma unroll
    for (int j = 0; j < 4; j++) s[i][j] = (f32x4){0.f, 0.f, 0.f, 0.f};
#pragma unroll
  for (int mt = 0; mt < 4; mt++)
#pragma unroll
    for (int nt = 0; nt < 4; nt++)
      s[mt][nt] = __builtin_amdgcn_mfma_f32_16x16x32_bf16(aq[mt], bk[nt], s[mt][nt], 0, 0, 0);

  const float* rb = relb + head * 4096;
  float rsum[4][4];
#pragma unroll
  for (int mt = 0; mt < 4; mt++) {
#pragma unroll
    for (int r = 0; r < 4; r++) {
      int row = mt * 16 + lhi * 4 + r;
      float vv[4];
      float vmax = -1e30f;
#pragma unroll
      for (int nt = 0; nt < 4; nt++) {
        int col = nt * 16 + l15;
        float v = s[mt][nt][r] * SCALE_F + rb[row * 64 + col];
        vv[nt] = v;
        vmax = fmaxf(vmax, v);
      }
#pragma unroll
      for (int d = 1; d < 16; d <<= 1) vmax = fmaxf(vmax, __shfl_xor(vmax, d, 64));
      float sum = 0.f;
#pragma unroll
      for (int nt = 0; nt < 4; nt++) {
        float p = __expf(vv[nt] - vmax);
        sum += p;
        p_lds[row * 72 + nt * 16 + l15] = f2bf(p);
      }
#pragma unroll
      for (int d = 1; d < 16; d <<= 1) sum += __shfl_xor(sum, d, 64);
      rsum[mt][r] = 1.f / sum;
    }
  }

  // stage v^T: vt[dh][token]
#pragma unroll
  for (int j = 0; j < 4; j++) {
    short8 vv = *(const short8*)(base + 512 + l * 768 + j * 8);
#pragma unroll
    for (int e = 0; e < 8; e++)
      vt_lds[(j * 8 + e) * 72 + l] = (unsigned short)vv[e];
  }
  __syncthreads();

  f32x4 o2[4][2];
#pragma unroll
  for (int i = 0; i < 4; i++) { o2[i][0] = (f32x4){0.f,0.f,0.f,0.f}; o2[i][1] = (f32x4){0.f,0.f,0.f,0.f}; }
#pragma unroll
  for (int ks = 0; ks < 2; ks++) {
    short8 ap[4], bv[2];
#pragma unroll
    for (int t = 0; t < 4; t++)
      ap[t] = *(const short8*)(&p_lds[(t * 16 + l15) * 72 + ks * 32 + lhi * 8]);
#pragma unroll
    for (int t = 0; t < 2; t++)
      bv[t] = *(const short8*)(&vt_lds[(t * 16 + l15) * 72 + ks * 32 + lhi * 8]);
#pragma unroll
    for (int mt = 0; mt < 4; mt++)
#pragma unroll
      for (int n2 = 0; n2 < 2; n2++)
        o2[mt][n2] = __builtin_amdgcn_mfma_f32_16x16x32_bf16(ap[mt], bv[n2], o2[mt][n2], 0, 0, 0);
  }
#pragma unroll
  for (int mt = 0; mt < 4; mt++)
#pragma unroll
    for (int n2 = 0; n2 < 2; n2++)
#pragma unroll
      for (int r = 0; r < 4; r++) {
        int row = mt * 16 + lhi * 4 + r;
        int dh = n2 * 16 + l15;
        o[((size_t)w * 64 + row) * 256 + head * 32 + dh] = f2bf(o2[mt][n2][r] * rsum[mt][r]);
      }
}

extern "C" void kernel_launch(void* const* d_in, const int* in_sizes, int n_in,
                              void* d_out, int out_size, void* d_ws, size_t ws_size,
                              hipStream_t stream) {
  (void)in_sizes; (void)n_in; (void)out_size;
  const float* x          = (const float*)d_in[0];
  const float* ln1_g      = (const float*)d_in[1];
  const float* ln1_b      = (const float*)d_in[2];
  const float* qkv_w      = (const float*)d_in[3];
  const float* qkv_b      = (const float*)d_in[4];
  const float* merge_w    = (const float*)d_in[5];
  const float* merge_b    = (const float*)d_in[6];
  const float* bias_table = (const float*)d_in[7];
  const float* ln2_g      = (const float*)d_in[8];
  const float* ln2_b      = (const float*)d_in[9];
  const float* mlp_w1     = (const float*)d_in[10];
  const float* mlp_b1     = (const float*)d_in[11];
  const float* mlp_w2     = (const float*)d_in[12];
  const float* mlp_b2     = (const float*)d_in[13];

  const size_t MB = 1024ull * 1024ull;
  char* ws = (char*)d_ws;
  // Fixed regions: 130 MiB total
  unsigned short* buf0 = (unsigned short*)(ws);             // 64 MiB: h -> attno -> h2
  unsigned short* x2   = (unsigned short*)(ws + 64 * MB);   // 64 MiB: bf16 residual-1 output
  unsigned short* wqkv = (unsigned short*)(ws + 128 * MB);  // [768][256] bf16
  unsigned short* wmrg = wqkv + 768 * 256;                  // [256][256]
  unsigned short* w1t  = wmrg + 256 * 256;                  // [1024][256]
  unsigned short* w2t  = w1t + 1024 * 256;                  // [256][1024]
  float* relb          = (float*)(w2t + 256 * 1024);        // [8][64][64] f32
  unsigned short* Cbuf = (unsigned short*)(ws + 130 * MB);  // adaptive scratch

  // Adaptive chunk sizes from ws_size (deterministic).
  size_t avail = ws_size > 130 * MB ? ws_size - 130 * MB : 0;
  int wc = 64;                                   // windows per qkv/attn chunk
  {
    const int cands[3] = {512, 256, 128};
    for (int i = 0; i < 3; i++)
      if ((size_t)cands[i] * 64 * 768 * 2 <= avail) { wc = cands[i]; break; }
  }
  int rc = 2048;                                 // rows per MLP chunk
  {
    const int cands[4] = {32768, 16384, 8192, 4096};
    for (int i = 0; i < 4; i++)
      if ((size_t)cands[i] * 1024 * 2 <= avail) { rc = cands[i]; break; }
  }

  cast_wt<256, 768><<<768, 256, 0, stream>>>(qkv_w, wqkv);
  cast_wt<256, 256><<<256, 256, 0, stream>>>(merge_w, wmrg);
  cast_wt<256, 1024><<<1024, 256, 0, stream>>>(mlp_w1, w1t);
  cast_wt<1024, 256><<<1024, 256, 0, stream>>>(mlp_w2, w2t);
  build_relb<<<128, 256, 0, stream>>>(bias_table, relb);

  part_ln1<<<1024, 256, 0, stream>>>(x, ln1_g, ln1_b, buf0);

  // QKV + attention, chunked over windows through Cbuf
  for (int w0 = 0; w0 < 2048; w0 += wc) {
    gemm_qkv<<<dim3(wc * 64 / 128, 6), 256, 0, stream>>>(
        buf0 + (size_t)w0 * 64 * 256, wqkv, qkv_b, nullptr, Cbuf, 256, 768, 0);
    attn_k<<<dim3(wc, 8), 64, 0, stream>>>(Cbuf, relb, buf0 + (size_t)w0 * 64 * 256);
  }

  // merge projection + residual(x gather, f32x4) -> x2 bf16
  gemm_merge<<<dim3(1024, 2), 256, 0, stream>>>(
      buf0, wmrg, merge_b, x, x2, 256, 256, 0);

  ln2k<<<32768, 256, 0, stream>>>(x2, ln2_g, ln2_b, buf0);

  // MLP, chunked over rows through Cbuf
  for (long r0 = 0; r0 < 131072; r0 += rc) {
    gemm_gelu<<<dim3(rc / 128, 8), 256, 0, stream>>>(
        buf0 + (size_t)r0 * 256, w1t, mlp_b1, nullptr, Cbuf, 256, 1024, 0);
    gemm_out<<<dim3(rc / 128, 2), 256, 0, stream>>>(
        Cbuf, w2t, mlp_b2, x2, d_out, 1024, 256, r0);
  }
}

// Round 7
// 747.166 us; speedup vs baseline: 1.2916x; 1.0404x over previous
//
#include <hip/hip_runtime.h>

typedef __attribute__((ext_vector_type(8))) short short8;
typedef __attribute__((ext_vector_type(4))) short short4v;
typedef __attribute__((ext_vector_type(8))) unsigned short ushort8v;
typedef __attribute__((ext_vector_type(4))) float f32x4;
typedef __attribute__((ext_vector_type(4))) int int4v;
typedef __attribute__((ext_vector_type(4))) unsigned short ushort4v;
typedef __attribute__((ext_vector_type(2))) unsigned short ushort2v;

#define SCALE_F 0.0625f   // C^-0.5 = 256^-0.5
#define EPS_F 1e-5f

__device__ __forceinline__ float bf2f(unsigned short u) {
  unsigned int i = ((unsigned int)u) << 16;
  return __builtin_bit_cast(float, i);
}
__device__ __forceinline__ unsigned short f2bf(float f) {
  unsigned int i = __builtin_bit_cast(unsigned int, f);
  i += 0x7fffu + ((i >> 16) & 1u);
  return (unsigned short)(i >> 16);
}

__device__ __forceinline__ void gload_lds16(const unsigned short* g, unsigned short* l) {
  __builtin_amdgcn_global_load_lds(
      (const __attribute__((address_space(1))) void*)g,
      (__attribute__((address_space(3))) void*)l, 16, 0, 0);
}

// ---- cast weight [K,N] f32 -> [N,K] bf16 (transposed) ----
template<int K, int N>
__global__ void cast_wt(const float* __restrict__ src, unsigned short* __restrict__ dst) {
  int id = blockIdx.x * 256 + threadIdx.x;          // id = n*K + k
  if (id >= K * N) return;
  int k = id % K, n = id / K;
  dst[id] = f2bf(src[(size_t)k * N + n]);
}

// ---- precompute relative-position bias [head][i][j] ----
__global__ void build_relb(const float* __restrict__ table, float* __restrict__ relb) {
  int id = blockIdx.x * 256 + threadIdx.x;          // 8*64*64
  int h = id >> 12, i = (id >> 6) & 63, j = id & 63;
  int dy = (i >> 3) - (j >> 3) + 7;
  int dx = (i & 7) - (j & 7) + 7;
  relb[id] = table[(dy * 15 + dx) * 8 + h];
}

// ---- window partition + LN1 (coalesced transpose): x[B,C,64,64] -> h bf16 [M,256] ----
#define PLN_RS 264   // LDS row stride in ushorts (256 + 8 pad)
__global__ __launch_bounds__(256) void part_ln1(
    const float* __restrict__ x, const float* __restrict__ g, const float* __restrict__ bb,
    unsigned short* __restrict__ h) {
  __shared__ __align__(16) unsigned short t_lds[128 * PLN_RS];
  __shared__ float ps_sum[128][2];
  __shared__ float ps_ss[128][2];
  const int tid = threadIdx.x;
  const int bid = blockIdx.x;
  const int b = bid >> 5, wr = (bid >> 2) & 7, cp = bid & 3;
  const int r0 = wr * 8;            // image row base
  const int c0 = cp * 16;           // image col base

  // Phase 1: coalesced read + transpose to LDS [px][ch]
  const int q = tid & 3, r = (tid >> 2) & 7, cb = tid >> 5;   // cb in 0..7
  const float* xb = x + (size_t)b * 256 * 4096 + (size_t)(r0 + r) * 64 + c0 + q * 4;
#pragma unroll
  for (int it = 0; it < 16; it++) {
    int cpair = it * 8 + cb;                 // channel pair 0..127
    const float* p0 = xb + (size_t)(2 * cpair) * 4096;
    f32x4 v0 = *(const f32x4*)p0;
    f32x4 v1 = *(const f32x4*)(p0 + 4096);
#pragma unroll
    for (int j = 0; j < 4; j++) {
      int px = r * 16 + q * 4 + j;
      ushort2v u = { f2bf(v0[j]), f2bf(v1[j]) };
      *(ushort2v*)(&t_lds[px * PLN_RS + 2 * cpair]) = u;
    }
  }
  __syncthreads();

  // Phase 2: per-pixel stats (2 threads per pixel)
  {
    const int p = tid & 127, half = tid >> 7;
    float sum = 0.f, ss = 0.f;
#pragma unroll
    for (int i = 0; i < 16; i++) {
      ushort8v u = *(const ushort8v*)(&t_lds[p * PLN_RS + half * 128 + i * 8]);
#pragma unroll
      for (int e = 0; e < 8; e++) { float f = bf2f(u[e]); sum += f; ss += f * f; }
    }
    ps_sum[p][half] = sum;
    ps_ss[p][half] = ss;
  }
  __syncthreads();

  // Phase 3: normalize + coalesced write
#pragma unroll
  for (int w = 0; w < 16; w++) {
    int id = w * 256 + tid;
    int p = id >> 5, ch = id & 31;
    float mu = (ps_sum[p][0] + ps_sum[p][1]) * (1.f / 256.f);
    float var = (ps_ss[p][0] + ps_ss[p][1]) * (1.f / 256.f) - mu * mu;
    float rs = rsqrtf(var + EPS_F);
    ushort8v u = *(const ushort8v*)(&t_lds[p * PLN_RS + ch * 8]);
    f32x4 g0 = *(const f32x4*)(g + ch * 8);
    f32x4 g1 = *(const f32x4*)(g + ch * 8 + 4);
    f32x4 b0 = *(const f32x4*)(bb + ch * 8);
    f32x4 b1 = *(const f32x4*)(bb + ch * 8 + 4);
    ushort8v o;
#pragma unroll
    for (int e = 0; e < 4; e++) {
      o[e]     = f2bf((bf2f(u[e])     - mu) * rs * g0[e] + b0[e]);
      o[e + 4] = f2bf((bf2f(u[e + 4]) - mu) * rs * g1[e] + b1[e]);
    }
    int rr = p >> 4, col = p & 15;
    size_t m = (size_t)b * 4096 + (size_t)(wr * 8 + cp * 2 + (col >> 3)) * 64 + rr * 8 + (col & 7);
    *(ushort8v*)(h + m * 256 + ch * 8) = o;
  }
}

// ---- LN2: x2 bf16 [M,256] -> h2 bf16 [M,256] ----
__global__ __launch_bounds__(256) void ln2k(
    const unsigned short* __restrict__ x2, const float* __restrict__ g, const float* __restrict__ bb,
    unsigned short* __restrict__ h2) {
  int m = blockIdx.x * 4 + (threadIdx.x >> 6);
  int l = threadIdx.x & 63;
  ushort4v u = *(const ushort4v*)(x2 + (size_t)m * 256 + l * 4);
  float v[4];
  float sum = 0.f, ss = 0.f;
#pragma unroll
  for (int j = 0; j < 4; j++) { v[j] = bf2f(u[j]); sum += v[j]; ss += v[j] * v[j]; }
#pragma unroll
  for (int d = 1; d < 64; d <<= 1) {
    sum += __shfl_xor(sum, d, 64);
    ss  += __shfl_xor(ss, d, 64);
  }
  float mu = sum * (1.f / 256.f);
  float var = ss * (1.f / 256.f) - mu * mu;
  float rs = rsqrtf(var + EPS_F);
  ushort4v oh;
#pragma unroll
  for (int j = 0; j < 4; j++) {
    int c = l * 4 + j;
    oh[j] = f2bf((v[j] - mu) * rs * g[c] + bb[c]);
  }
  *(ushort4v*)(h2 + (size_t)m * 256 + l * 4) = oh;
}

// ---- GEMM: A bf16 [rows,K] x Bt bf16 [N,K] -> out, 128x128 tile, 4 waves ----
enum { EPI_QKV = 0, EPI_MERGE = 1 };

template<int EPI>
__device__ __forceinline__ void gemm_body(
    unsigned short* As, unsigned short* Bs,
    const unsigned short* __restrict__ A, const unsigned short* __restrict__ Bt,
    const float* __restrict__ bias, const void* __restrict__ res,
    void* __restrict__ out, int K, int N, long m_base) {
  const int tid = threadIdx.x;
  const int l15 = tid & 15, lhi = (tid & 63) >> 4;
  const int wid = tid >> 6, wm = wid >> 1, wn = wid & 1;
  const size_t m0 = (size_t)blockIdx.x * 128;
  const int n0 = blockIdx.y * 128;
  const int row_s = tid >> 3, kc8 = (tid & 7) * 8;   // staging coords

  auto stage = [&](int kb, int k0) {
#pragma unroll
    for (int i = 0; i < 4; i++) {
      int row = i * 32 + row_s;
      gload_lds16(A + (m0 + row) * (size_t)K + k0 + kc8, &As[kb * 8192 + (i * 256 + tid) * 8]);
      gload_lds16(Bt + (size_t)(n0 + row) * (size_t)K + k0 + kc8, &Bs[kb * 8192 + (i * 256 + tid) * 8]);
    }
  };

  f32x4 acc[4][4];
#pragma unroll
  for (int i = 0; i < 4; i++)
#pragma unroll
    for (int j = 0; j < 4; j++) acc[i][j] = (f32x4){0.f, 0.f, 0.f, 0.f};

  stage(0, 0);
  int kb = 0;
  for (int k0 = 0; k0 < K; k0 += 64, kb ^= 1) {
    if (k0 + 64 < K) {
      stage(kb ^ 1, k0 + 64);
      asm volatile("s_waitcnt vmcnt(8)" ::: "memory");
    } else {
      asm volatile("s_waitcnt vmcnt(0)" ::: "memory");
    }
    __builtin_amdgcn_s_barrier();
#pragma unroll
    for (int ks = 0; ks < 2; ks++) {
      short8 af[4], bfr[4];
#pragma unroll
      for (int t = 0; t < 4; t++) {
        af[t]  = *(const short8*)(&As[kb * 8192 + (wm * 64 + t * 16 + l15) * 64 + ks * 32 + lhi * 8]);
        bfr[t] = *(const short8*)(&Bs[kb * 8192 + (wn * 64 + t * 16 + l15) * 64 + ks * 32 + lhi * 8]);
      }
#pragma unroll
      for (int mt = 0; mt < 4; mt++)
#pragma unroll
        for (int nt = 0; nt < 4; nt++)
          acc[mt][nt] = __builtin_amdgcn_mfma_f32_16x16x32_bf16(af[mt], bfr[nt], acc[mt][nt], 0, 0, 0);
    }
    __builtin_amdgcn_s_barrier();
  }

#pragma unroll
  for (int mt = 0; mt < 4; mt++) {
#pragma unroll
    for (int nt = 0; nt < 4; nt++) {
      const size_t gml0 = m0 + wm * 64 + mt * 16 + lhi * 4;
      const size_t gm0 = gml0 + (size_t)m_base;
      const int gn = n0 + wn * 64 + nt * 16 + l15;
      if (EPI == EPI_QKV) {
#pragma unroll
        for (int r = 0; r < 4; r++)
          ((unsigned short*)out)[(gml0 + r) * (size_t)N + gn] = f2bf(acc[mt][nt][r] + bias[gn]);
      } else {  // EPI_MERGE: r=0..3 consecutive pixels in one image row -> one f32x4 gather
        int bi = (int)(gm0 >> 12), gg = (int)((gm0 >> 6) & 63), s0 = (int)(gm0 & 63);
        size_t sp = (size_t)((gg >> 3) * 8 + (s0 >> 3)) * 64 + (gg & 7) * 8 + (s0 & 7);
        f32x4 xr = *(const f32x4*)(&((const float*)res)[((size_t)(bi * 256 + gn)) * 4096 + sp]);
#pragma unroll
        for (int r = 0; r < 4; r++)
          ((unsigned short*)out)[(gm0 + r) * 256 + gn] = f2bf(acc[mt][nt][r] + bias[gn] + xr[r]);
      }
    }
  }
}

#define GEMM_WRAP(name, epi)                                                          \
__global__ __launch_bounds__(256) void name(                                          \
    const unsigned short* __restrict__ A, const unsigned short* __restrict__ Bt,      \
    const float* __restrict__ bias, const void* __restrict__ res,                     \
    void* __restrict__ out, int K, int N, long m_base) {                              \
  __shared__ __align__(16) unsigned short As[2 * 128 * 64];                           \
  __shared__ __align__(16) unsigned short Bs[2 * 128 * 64];                           \
  gemm_body<epi>(As, Bs, A, Bt, bias, res, out, K, N, m_base);                        \
}
GEMM_WRAP(gemm_qkv, EPI_QKV)
GEMM_WRAP(gemm_merge, EPI_MERGE)

// ---- fused MLP: h2[M,256] -> GELU(h2@w1+b1)@w2+b2 + x2 -> departition -> out ----
// Block = 64 tokens, 4 waves. Hidden (1024) processed in 8 slices of 128.
// Ash: [64][256] bf16, 16B-unit XOR swizzle (su = gu ^ ((row&15)<<1)).
// A2sh: [64][132] bf16 (stride 132 elems = 264B; b64 frag reads conflict-optimal).
#define A2S 132
__global__ __launch_bounds__(256, 2) void mlp_fused(
    const unsigned short* __restrict__ h2, const unsigned short* __restrict__ w1t,
    const float* __restrict__ b1, const unsigned short* __restrict__ w2t,
    const float* __restrict__ b2, const unsigned short* __restrict__ x2,
    float* __restrict__ out) {
  __shared__ __align__(16) unsigned short Ash[64 * 256];
  __shared__ __align__(16) unsigned short A2sh[64 * A2S];
  const int tid = threadIdx.x;
  const int wid = tid >> 6, l = tid & 63, l15 = l & 15, lhi = l >> 4;
  const size_t m0 = (size_t)blockIdx.x * 64;

  // stage h2 rows into Ash with 16B-unit swizzle (linear LDS dest, pre-swizzled src)
#pragma unroll
  for (int i = 0; i < 8; i++) {
    int uidx = i * 256 + tid;
    int row = uidx >> 5, su = uidx & 31;
    int gu = su ^ ((row & 15) << 1);
    gload_lds16(h2 + (m0 + row) * 256 + gu * 8, &Ash[uidx * 8]);
  }
  asm volatile("s_waitcnt vmcnt(0)" ::: "memory");
  __builtin_amdgcn_s_barrier();

  f32x4 oacc[4][4];
#pragma unroll
  for (int i = 0; i < 4; i++)
#pragma unroll
    for (int j = 0; j < 4; j++) oacc[i][j] = (f32x4){0.f, 0.f, 0.f, 0.f};

  for (int hs = 0; hs < 8; hs++) {
    // GEMM1: hidden[64 tok][32 cols-per-wave], K=256
    f32x4 hacc[4][2];
#pragma unroll
    for (int i = 0; i < 4; i++) { hacc[i][0] = (f32x4){0.f,0.f,0.f,0.f}; hacc[i][1] = (f32x4){0.f,0.f,0.f,0.f}; }
    const int hc0 = hs * 128 + wid * 32;
#pragma unroll
    for (int kst = 0; kst < 8; kst++) {
      short8 af[4], bf1[2];
#pragma unroll
      for (int mt = 0; mt < 4; mt++) {
        int su = (kst * 4 + lhi) ^ ((l15 & 15) << 1);
        af[mt] = *(const short8*)(&Ash[(mt * 16 + l15) * 256 + su * 8]);
      }
#pragma unroll
      for (int nt = 0; nt < 2; nt++)
        bf1[nt] = *(const short8*)(w1t + (size_t)(hc0 + nt * 16 + l15) * 256 + kst * 32 + lhi * 8);
#pragma unroll
      for (int mt = 0; mt < 4; mt++)
#pragma unroll
        for (int nt = 0; nt < 2; nt++)
          hacc[mt][nt] = __builtin_amdgcn_mfma_f32_16x16x32_bf16(af[mt], bf1[nt], hacc[mt][nt], 0, 0, 0);
    }
    // bias + GELU -> A2sh
    float bv0 = b1[hc0 + l15], bv1 = b1[hc0 + 16 + l15];
#pragma unroll
    for (int mt = 0; mt < 4; mt++)
#pragma unroll
      for (int nt = 0; nt < 2; nt++) {
        float bv = nt ? bv1 : bv0;
        int kh = wid * 32 + nt * 16 + l15;
#pragma unroll
        for (int rr = 0; rr < 4; rr++) {
          float v = hacc[mt][nt][rr] + bv;
          float gl = 0.5f * v * (1.f + erff(v * 0.70710678118f));
          A2sh[(mt * 16 + lhi * 4 + rr) * A2S + kh] = f2bf(gl);
        }
      }
    __builtin_amdgcn_s_barrier();
    // GEMM2: out[64 tok][64 oc-per-wave] += A2[64][128] x w2t-slice
#pragma unroll
    for (int k2 = 0; k2 < 4; k2++) {
      short8 a2[4], bf2v[4];
#pragma unroll
      for (int mt = 0; mt < 4; mt++) {
        const unsigned short* p = &A2sh[(mt * 16 + l15) * A2S + k2 * 32 + lhi * 8];
        short4v lo = *(const short4v*)p;
        short4v hi = *(const short4v*)(p + 4);
        a2[mt] = (short8){lo[0], lo[1], lo[2], lo[3], hi[0], hi[1], hi[2], hi[3]};
      }
#pragma unroll
      for (int nt = 0; nt < 4; nt++)
        bf2v[nt] = *(const short8*)(w2t + (size_t)(wid * 64 + nt * 16 + l15) * 1024 +
                                    hs * 128 + k2 * 32 + lhi * 8);
#pragma unroll
      for (int mt = 0; mt < 4; mt++)
#pragma unroll
        for (int nt = 0; nt < 4; nt++)
          oacc[mt][nt] = __builtin_amdgcn_mfma_f32_16x16x32_bf16(a2[mt], bf2v[nt], oacc[mt][nt], 0, 0, 0);
    }
    __builtin_amdgcn_s_barrier();   // A2sh reuse next slice
  }

  // epilogue: + b2 + x2 residual, departition scatter (f32x4)
#pragma unroll
  for (int mt = 0; mt < 4; mt++) {
#pragma unroll
    for (int nt = 0; nt < 4; nt++) {
      size_t gm0 = m0 + mt * 16 + lhi * 4;
      int gn = wid * 64 + nt * 16 + l15;
      int bi = (int)(gm0 >> 12), gg = (int)((gm0 >> 6) & 63), s0 = (int)(gm0 & 63);
      size_t sp = (size_t)((gg >> 3) * 8 + (s0 >> 3)) * 64 + (gg & 7) * 8 + (s0 & 7);
      f32x4 o4;
#pragma unroll
      for (int r = 0; r < 4; r++)
        o4[r] = oacc[mt][nt][r] + b2[gn] + bf2f(x2[(gm0 + r) * 256 + gn]);
      *(f32x4*)(&out[((size_t)(bi * 256 + gn)) * 4096 + sp]) = o4;
    }
  }
}

// ---- attention: one wave per (window, head) ----
__global__ __launch_bounds__(64) void attn_k(
    const unsigned short* __restrict__ qkv, const float* __restrict__ relb,
    unsigned short* __restrict__ o) {
  __shared__ __align__(16) unsigned short p_lds[64 * 72];
  __shared__ __align__(16) unsigned short vt_lds[32 * 72];
  const int l = threadIdx.x;
  const int l15 = l & 15, lhi = l >> 4;
  const int w = blockIdx.x, head = blockIdx.y;
  const unsigned short* base = qkv + (size_t)w * 64 * 768 + head * 32;

  short8 aq[4], bk[4];
#pragma unroll
  for (int t = 0; t < 4; t++) {
    aq[t] = *(const short8*)(base + (t * 16 + l15) * 768 + lhi * 8);
    bk[t] = *(const short8*)(base + 256 + (t * 16 + l15) * 768 + lhi * 8);
  }
  f32x4 s[4][4];
#pragma unroll
  for (int i = 0; i < 4; i++)
#pragma unroll
    for (int j = 0; j < 4; j++) s[i][j] = (f32x4){0.f, 0.f, 0.f, 0.f};
#pragma unroll
  for (int mt = 0; mt < 4; mt++)
#pragma unroll
    for (int nt = 0; nt < 4; nt++)
      s[mt][nt] = __builtin_amdgcn_mfma_f32_16x16x32_bf16(aq[mt], bk[nt], s[mt][nt], 0, 0, 0);

  const float* rb = relb + head * 4096;
  float rsum[4][4];
#pragma unroll
  for (int mt = 0; mt < 4; mt++) {
#pragma unroll
    for (int r = 0; r < 4; r++) {
      int row = mt * 16 + lhi * 4 + r;
      float vv[4];
      float vmax = -1e30f;
#pragma unroll
      for (int nt = 0; nt < 4; nt++) {
        int col = nt * 16 + l15;
        float v = s[mt][nt][r] * SCALE_F + rb[row * 64 + col];
        vv[nt] = v;
        vmax = fmaxf(vmax, v);
      }
#pragma unroll
      for (int d = 1; d < 16; d <<= 1) vmax = fmaxf(vmax, __shfl_xor(vmax, d, 64));
      float sum = 0.f;
#pragma unroll
      for (int nt = 0; nt < 4; nt++) {
        float p = __expf(vv[nt] - vmax);
        sum += p;
        p_lds[row * 72 + nt * 16 + l15] = f2bf(p);
      }
#pragma unroll
      for (int d = 1; d < 16; d <<= 1) sum += __shfl_xor(sum, d, 64);
      rsum[mt][r] = 1.f / sum;
    }
  }

  // stage v^T: vt[dh][token]
#pragma unroll
  for (int j = 0; j < 4; j++) {
    short8 vv = *(const short8*)(base + 512 + l * 768 + j * 8);
#pragma unroll
    for (int e = 0; e < 8; e++)
      vt_lds[(j * 8 + e) * 72 + l] = (unsigned short)vv[e];
  }
  __syncthreads();

  f32x4 o2[4][2];
#pragma unroll
  for (int i = 0; i < 4; i++) { o2[i][0] = (f32x4){0.f,0.f,0.f,0.f}; o2[i][1] = (f32x4){0.f,0.f,0.f,0.f}; }
#pragma unroll
  for (int ks = 0; ks < 2; ks++) {
    short8 ap[4], bv[2];
#pragma unroll
    for (int t = 0; t < 4; t++)
      ap[t] = *(const short8*)(&p_lds[(t * 16 + l15) * 72 + ks * 32 + lhi * 8]);
#pragma unroll
    for (int t = 0; t < 2; t++)
      bv[t] = *(const short8*)(&vt_lds[(t * 16 + l15) * 72 + ks * 32 + lhi * 8]);
#pragma unroll
    for (int mt = 0; mt < 4; mt++)
#pragma unroll
      for (int n2 = 0; n2 < 2; n2++)
        o2[mt][n2] = __builtin_amdgcn_mfma_f32_16x16x32_bf16(ap[mt], bv[n2], o2[mt][n2], 0, 0, 0);
  }
#pragma unroll
  for (int mt = 0; mt < 4; mt++)
#pragma unroll
    for (int n2 = 0; n2 < 2; n2++)
#pragma unroll
      for (int r = 0; r < 4; r++) {
        int row = mt * 16 + lhi * 4 + r;
        int dh = n2 * 16 + l15;
        o[((size_t)w * 64 + row) * 256 + head * 32 + dh] = f2bf(o2[mt][n2][r] * rsum[mt][r]);
      }
}

extern "C" void kernel_launch(void* const* d_in, const int* in_sizes, int n_in,
                              void* d_out, int out_size, void* d_ws, size_t ws_size,
                              hipStream_t stream) {
  (void)in_sizes; (void)n_in; (void)out_size;
  const float* x          = (const float*)d_in[0];
  const float* ln1_g      = (const float*)d_in[1];
  const float* ln1_b      = (const float*)d_in[2];
  const float* qkv_w      = (const float*)d_in[3];
  const float* qkv_b      = (const float*)d_in[4];
  const float* merge_w    = (const float*)d_in[5];
  const float* merge_b    = (const float*)d_in[6];
  const float* bias_table = (const float*)d_in[7];
  const float* ln2_g      = (const float*)d_in[8];
  const float* ln2_b      = (const float*)d_in[9];
  const float* mlp_w1     = (const float*)d_in[10];
  const float* mlp_b1     = (const float*)d_in[11];
  const float* mlp_w2     = (const float*)d_in[12];
  const float* mlp_b2     = (const float*)d_in[13];

  const size_t MB = 1024ull * 1024ull;
  char* ws = (char*)d_ws;
  unsigned short* buf0 = (unsigned short*)(ws);             // 64 MiB: h -> attno -> h2
  unsigned short* x2   = (unsigned short*)(ws + 64 * MB);   // 64 MiB: bf16 residual-1
  unsigned short* wqkv = (unsigned short*)(ws + 128 * MB);  // [768][256] bf16
  unsigned short* wmrg = wqkv + 768 * 256;                  // [256][256]
  unsigned short* w1t  = wmrg + 256 * 256;                  // [1024][256]
  unsigned short* w2t  = w1t + 1024 * 256;                  // [256][1024]
  float* relb          = (float*)(w2t + 256 * 1024);        // [8][64][64] f32
  unsigned short* Cbuf = (unsigned short*)(ws + 130 * MB);  // qkv chunk scratch

  size_t avail = ws_size > 130 * MB ? ws_size - 130 * MB : 0;
  int wc = 64;                                   // windows per qkv/attn chunk
  {
    const int cands[3] = {512, 256, 128};
    for (int i = 0; i < 3; i++)
      if ((size_t)cands[i] * 64 * 768 * 2 <= avail) { wc = cands[i]; break; }
  }

  cast_wt<256, 768><<<768, 256, 0, stream>>>(qkv_w, wqkv);
  cast_wt<256, 256><<<256, 256, 0, stream>>>(merge_w, wmrg);
  cast_wt<256, 1024><<<1024, 256, 0, stream>>>(mlp_w1, w1t);
  cast_wt<1024, 256><<<1024, 256, 0, stream>>>(mlp_w2, w2t);
  build_relb<<<128, 256, 0, stream>>>(bias_table, relb);

  part_ln1<<<1024, 256, 0, stream>>>(x, ln1_g, ln1_b, buf0);

  for (int w0 = 0; w0 < 2048; w0 += wc) {
    gemm_qkv<<<dim3(wc * 64 / 128, 6), 256, 0, stream>>>(
        buf0 + (size_t)w0 * 64 * 256, wqkv, qkv_b, nullptr, Cbuf, 256, 768, 0);
    attn_k<<<dim3(wc, 8), 64, 0, stream>>>(Cbuf, relb, buf0 + (size_t)w0 * 64 * 256);
  }

  gemm_merge<<<dim3(1024, 2), 256, 0, stream>>>(
      buf0, wmrg, merge_b, x, x2, 256, 256, 0);

  ln2k<<<32768, 256, 0, stream>>>(x2, ln2_g, ln2_b, buf0);

  mlp_fused<<<2048, 256, 0, stream>>>(buf0, w1t, mlp_b1, w2t, mlp_b2, x2, (float*)d_out);
}

// Round 8
// 741.606 us; speedup vs baseline: 1.3012x; 1.0075x over previous
//
#include <hip/hip_runtime.h>

typedef __attribute__((ext_vector_type(8))) short short8;
typedef __attribute__((ext_vector_type(4))) short short4v;
typedef __attribute__((ext_vector_type(8))) unsigned short ushort8v;
typedef __attribute__((ext_vector_type(4))) float f32x4;
typedef __attribute__((ext_vector_type(4))) int int4v;
typedef __attribute__((ext_vector_type(4))) unsigned short ushort4v;
typedef __attribute__((ext_vector_type(2))) unsigned short ushort2v;

#define SCALE_F 0.0625f   // C^-0.5 = 256^-0.5
#define EPS_F 1e-5f

__device__ __forceinline__ float bf2f(unsigned short u) {
  unsigned int i = ((unsigned int)u) << 16;
  return __builtin_bit_cast(float, i);
}
__device__ __forceinline__ unsigned short f2bf(float f) {
  unsigned int i = __builtin_bit_cast(unsigned int, f);
  i += 0x7fffu + ((i >> 16) & 1u);
  return (unsigned short)(i >> 16);
}

// tanh-form GELU: 0.5v(1+tanh(0.79788456(v+0.044715v^3)))
//  = v - v*rcp(exp(2t)+1), 2t = v*(1.59576912 + 0.07135482 v^2)
// ~10 VALU ops vs ~27 for erff; |err| < 5e-4 for |v|<2 (our sigma ~0.32).
__device__ __forceinline__ float fast_gelu(float v) {
  float s = v * v;
  float u = v * __builtin_fmaf(s, 0.0713548163f, 1.5957691216f);
  float e = __expf(u);
  float r = __builtin_amdgcn_rcpf(e + 1.f);
  return v - v * r;
}

__device__ __forceinline__ void gload_lds16(const unsigned short* g, unsigned short* l) {
  __builtin_amdgcn_global_load_lds(
      (const __attribute__((address_space(1))) void*)g,
      (__attribute__((address_space(3))) void*)l, 16, 0, 0);
}

// ---- cast weight [K,N] f32 -> [N,K] bf16 (transposed) ----
template<int K, int N>
__global__ void cast_wt(const float* __restrict__ src, unsigned short* __restrict__ dst) {
  int id = blockIdx.x * 256 + threadIdx.x;          // id = n*K + k
  if (id >= K * N) return;
  int k = id % K, n = id / K;
  dst[id] = f2bf(src[(size_t)k * N + n]);
}

// ---- precompute relative-position bias [head][i][j] ----
__global__ void build_relb(const float* __restrict__ table, float* __restrict__ relb) {
  int id = blockIdx.x * 256 + threadIdx.x;          // 8*64*64
  int h = id >> 12, i = (id >> 6) & 63, j = id & 63;
  int dy = (i >> 3) - (j >> 3) + 7;
  int dx = (i & 7) - (j & 7) + 7;
  relb[id] = table[(dy * 15 + dx) * 8 + h];
}

// ---- window partition + LN1 (coalesced transpose): x[B,C,64,64] -> h bf16 [M,256] ----
#define PLN_RS 264   // LDS row stride in ushorts (256 + 8 pad)
__global__ __launch_bounds__(256) void part_ln1(
    const float* __restrict__ x, const float* __restrict__ g, const float* __restrict__ bb,
    unsigned short* __restrict__ h) {
  __shared__ __align__(16) unsigned short t_lds[128 * PLN_RS];
  __shared__ float ps_sum[128][2];
  __shared__ float ps_ss[128][2];
  const int tid = threadIdx.x;
  const int bid = blockIdx.x;
  const int b = bid >> 5, wr = (bid >> 2) & 7, cp = bid & 3;
  const int r0 = wr * 8;            // image row base
  const int c0 = cp * 16;           // image col base

  // Phase 1: coalesced read + transpose to LDS [px][ch]
  const int q = tid & 3, r = (tid >> 2) & 7, cb = tid >> 5;   // cb in 0..7
  const float* xb = x + (size_t)b * 256 * 4096 + (size_t)(r0 + r) * 64 + c0 + q * 4;
#pragma unroll
  for (int it = 0; it < 16; it++) {
    int cpair = it * 8 + cb;                 // channel pair 0..127
    const float* p0 = xb + (size_t)(2 * cpair) * 4096;
    f32x4 v0 = *(const f32x4*)p0;
    f32x4 v1 = *(const f32x4*)(p0 + 4096);
#pragma unroll
    for (int j = 0; j < 4; j++) {
      int px = r * 16 + q * 4 + j;
      ushort2v u = { f2bf(v0[j]), f2bf(v1[j]) };
      *(ushort2v*)(&t_lds[px * PLN_RS + 2 * cpair]) = u;
    }
  }
  __syncthreads();

  // Phase 2: per-pixel stats (2 threads per pixel)
  {
    const int p = tid & 127, half = tid >> 7;
    float sum = 0.f, ss = 0.f;
#pragma unroll
    for (int i = 0; i < 16; i++) {
      ushort8v u = *(const ushort8v*)(&t_lds[p * PLN_RS + half * 128 + i * 8]);
#pragma unroll
      for (int e = 0; e < 8; e++) { float f = bf2f(u[e]); sum += f; ss += f * f; }
    }
    ps_sum[p][half] = sum;
    ps_ss[p][half] = ss;
  }
  __syncthreads();

  // Phase 3: normalize + coalesced write
#pragma unroll
  for (int w = 0; w < 16; w++) {
    int id = w * 256 + tid;
    int p = id >> 5, ch = id & 31;
    float mu = (ps_sum[p][0] + ps_sum[p][1]) * (1.f / 256.f);
    float var = (ps_ss[p][0] + ps_ss[p][1]) * (1.f / 256.f) - mu * mu;
    float rs = rsqrtf(var + EPS_F);
    ushort8v u = *(const ushort8v*)(&t_lds[p * PLN_RS + ch * 8]);
    f32x4 g0 = *(const f32x4*)(g + ch * 8);
    f32x4 g1 = *(const f32x4*)(g + ch * 8 + 4);
    f32x4 b0 = *(const f32x4*)(bb + ch * 8);
    f32x4 b1 = *(const f32x4*)(bb + ch * 8 + 4);
    ushort8v o;
#pragma unroll
    for (int e = 0; e < 4; e++) {
      o[e]     = f2bf((bf2f(u[e])     - mu) * rs * g0[e] + b0[e]);
      o[e + 4] = f2bf((bf2f(u[e + 4]) - mu) * rs * g1[e] + b1[e]);
    }
    int rr = p >> 4, col = p & 15;
    size_t m = (size_t)b * 4096 + (size_t)(wr * 8 + cp * 2 + (col >> 3)) * 64 + rr * 8 + (col & 7);
    *(ushort8v*)(h + m * 256 + ch * 8) = o;
  }
}

// ---- LN2: x2 bf16 [M,256] -> h2 bf16 [M,256] ----
__global__ __launch_bounds__(256) void ln2k(
    const unsigned short* __restrict__ x2, const float* __restrict__ g, const float* __restrict__ bb,
    unsigned short* __restrict__ h2) {
  int m = blockIdx.x * 4 + (threadIdx.x >> 6);
  int l = threadIdx.x & 63;
  ushort4v u = *(const ushort4v*)(x2 + (size_t)m * 256 + l * 4);
  float v[4];
  float sum = 0.f, ss = 0.f;
#pragma unroll
  for (int j = 0; j < 4; j++) { v[j] = bf2f(u[j]); sum += v[j]; ss += v[j] * v[j]; }
#pragma unroll
  for (int d = 1; d < 64; d <<= 1) {
    sum += __shfl_xor(sum, d, 64);
    ss  += __shfl_xor(ss, d, 64);
  }
  float mu = sum * (1.f / 256.f);
  float var = ss * (1.f / 256.f) - mu * mu;
  float rs = rsqrtf(var + EPS_F);
  ushort4v oh;
#pragma unroll
  for (int j = 0; j < 4; j++) {
    int c = l * 4 + j;
    oh[j] = f2bf((v[j] - mu) * rs * g[c] + bb[c]);
  }
  *(ushort4v*)(h2 + (size_t)m * 256 + l * 4) = oh;
}

// ---- GEMM: A bf16 [rows,K] x Bt bf16 [N,K] -> out, 128x128 tile, 4 waves ----
enum { EPI_QKV = 0, EPI_MERGE = 1 };

template<int EPI>
__device__ __forceinline__ void gemm_body(
    unsigned short* As, unsigned short* Bs,
    const unsigned short* __restrict__ A, const unsigned short* __restrict__ Bt,
    const float* __restrict__ bias, const void* __restrict__ res,
    void* __restrict__ out, int K, int N, long m_base) {
  const int tid = threadIdx.x;
  const int l15 = tid & 15, lhi = (tid & 63) >> 4;
  const int wid = tid >> 6, wm = wid >> 1, wn = wid & 1;
  const size_t m0 = (size_t)blockIdx.x * 128;
  const int n0 = blockIdx.y * 128;
  const int row_s = tid >> 3, kc8 = (tid & 7) * 8;   // staging coords

  auto stage = [&](int kb, int k0) {
#pragma unroll
    for (int i = 0; i < 4; i++) {
      int row = i * 32 + row_s;
      gload_lds16(A + (m0 + row) * (size_t)K + k0 + kc8, &As[kb * 8192 + (i * 256 + tid) * 8]);
      gload_lds16(Bt + (size_t)(n0 + row) * (size_t)K + k0 + kc8, &Bs[kb * 8192 + (i * 256 + tid) * 8]);
    }
  };

  f32x4 acc[4][4];
#pragma unroll
  for (int i = 0; i < 4; i++)
#pragma unroll
    for (int j = 0; j < 4; j++) acc[i][j] = (f32x4){0.f, 0.f, 0.f, 0.f};

  stage(0, 0);
  int kb = 0;
  for (int k0 = 0; k0 < K; k0 += 64, kb ^= 1) {
    if (k0 + 64 < K) {
      stage(kb ^ 1, k0 + 64);
      asm volatile("s_waitcnt vmcnt(8)" ::: "memory");
    } else {
      asm volatile("s_waitcnt vmcnt(0)" ::: "memory");
    }
    __builtin_amdgcn_s_barrier();
#pragma unroll
    for (int ks = 0; ks < 2; ks++) {
      short8 af[4], bfr[4];
#pragma unroll
      for (int t = 0; t < 4; t++) {
        af[t]  = *(const short8*)(&As[kb * 8192 + (wm * 64 + t * 16 + l15) * 64 + ks * 32 + lhi * 8]);
        bfr[t] = *(const short8*)(&Bs[kb * 8192 + (wn * 64 + t * 16 + l15) * 64 + ks * 32 + lhi * 8]);
      }
#pragma unroll
      for (int mt = 0; mt < 4; mt++)
#pragma unroll
        for (int nt = 0; nt < 4; nt++)
          acc[mt][nt] = __builtin_amdgcn_mfma_f32_16x16x32_bf16(af[mt], bfr[nt], acc[mt][nt], 0, 0, 0);
    }
    __builtin_amdgcn_s_barrier();
  }

#pragma unroll
  for (int mt = 0; mt < 4; mt++) {
#pragma unroll
    for (int nt = 0; nt < 4; nt++) {
      const size_t gml0 = m0 + wm * 64 + mt * 16 + lhi * 4;
      const size_t gm0 = gml0 + (size_t)m_base;
      const int gn = n0 + wn * 64 + nt * 16 + l15;
      if (EPI == EPI_QKV) {
#pragma unroll
        for (int r = 0; r < 4; r++)
          ((unsigned short*)out)[(gml0 + r) * (size_t)N + gn] = f2bf(acc[mt][nt][r] + bias[gn]);
      } else {  // EPI_MERGE: r=0..3 consecutive pixels in one image row -> one f32x4 gather
        int bi = (int)(gm0 >> 12), gg = (int)((gm0 >> 6) & 63), s0 = (int)(gm0 & 63);
        size_t sp = (size_t)((gg >> 3) * 8 + (s0 >> 3)) * 64 + (gg & 7) * 8 + (s0 & 7);
        f32x4 xr = *(const f32x4*)(&((const float*)res)[((size_t)(bi * 256 + gn)) * 4096 + sp]);
#pragma unroll
        for (int r = 0; r < 4; r++)
          ((unsigned short*)out)[(gm0 + r) * 256 + gn] = f2bf(acc[mt][nt][r] + bias[gn] + xr[r]);
      }
    }
  }
}

#define GEMM_WRAP(name, epi)                                                          \
__global__ __launch_bounds__(256) void name(                                          \
    const unsigned short* __restrict__ A, const unsigned short* __restrict__ Bt,      \
    const float* __restrict__ bias, const void* __restrict__ res,                     \
    void* __restrict__ out, int K, int N, long m_base) {                              \
  __shared__ __align__(16) unsigned short As[2 * 128 * 64];                           \
  __shared__ __align__(16) unsigned short Bs[2 * 128 * 64];                           \
  gemm_body<epi>(As, Bs, A, Bt, bias, res, out, K, N, m_base);                        \
}
GEMM_WRAP(gemm_qkv, EPI_QKV)
GEMM_WRAP(gemm_merge, EPI_MERGE)

// ---- fused MLP: h2[M,256] -> GELU(h2@w1+b1)@w2+b2 + x2 -> departition -> out ----
// Block = 64 tokens, 4 waves. Hidden (1024) processed in 8 slices of 128.
#define A2S 132
__global__ __launch_bounds__(256, 2) void mlp_fused(
    const unsigned short* __restrict__ h2, const unsigned short* __restrict__ w1t,
    const float* __restrict__ b1, const unsigned short* __restrict__ w2t,
    const float* __restrict__ b2, const unsigned short* __restrict__ x2,
    float* __restrict__ out) {
  __shared__ __align__(16) unsigned short Ash[64 * 256];
  __shared__ __align__(16) unsigned short A2sh[64 * A2S];
  const int tid = threadIdx.x;
  const int wid = tid >> 6, l = tid & 63, l15 = l & 15, lhi = l >> 4;
  const size_t m0 = (size_t)blockIdx.x * 64;

  // stage h2 rows into Ash with 16B-unit swizzle (linear LDS dest, pre-swizzled src)
#pragma unroll
  for (int i = 0; i < 8; i++) {
    int uidx = i * 256 + tid;
    int row = uidx >> 5, su = uidx & 31;
    int gu = su ^ ((row & 15) << 1);
    gload_lds16(h2 + (m0 + row) * 256 + gu * 8, &Ash[uidx * 8]);
  }
  asm volatile("s_waitcnt vmcnt(0)" ::: "memory");
  __builtin_amdgcn_s_barrier();

  f32x4 oacc[4][4];
#pragma unroll
  for (int i = 0; i < 4; i++)
#pragma unroll
    for (int j = 0; j < 4; j++) oacc[i][j] = (f32x4){0.f, 0.f, 0.f, 0.f};

  for (int hs = 0; hs < 8; hs++) {
    // GEMM1: hidden[64 tok][32 cols-per-wave], K=256
    f32x4 hacc[4][2];
#pragma unroll
    for (int i = 0; i < 4; i++) { hacc[i][0] = (f32x4){0.f,0.f,0.f,0.f}; hacc[i][1] = (f32x4){0.f,0.f,0.f,0.f}; }
    const int hc0 = hs * 128 + wid * 32;
#pragma unroll
    for (int kst = 0; kst < 8; kst++) {
      short8 af[4], bf1[2];
#pragma unroll
      for (int mt = 0; mt < 4; mt++) {
        int su = (kst * 4 + lhi) ^ ((l15 & 15) << 1);
        af[mt] = *(const short8*)(&Ash[(mt * 16 + l15) * 256 + su * 8]);
      }
#pragma unroll
      for (int nt = 0; nt < 2; nt++)
        bf1[nt] = *(const short8*)(w1t + (size_t)(hc0 + nt * 16 + l15) * 256 + kst * 32 + lhi * 8);
#pragma unroll
      for (int mt = 0; mt < 4; mt++)
#pragma unroll
        for (int nt = 0; nt < 2; nt++)
          hacc[mt][nt] = __builtin_amdgcn_mfma_f32_16x16x32_bf16(af[mt], bf1[nt], hacc[mt][nt], 0, 0, 0);
    }
    // bias + GELU -> A2sh
    float bv0 = b1[hc0 + l15], bv1 = b1[hc0 + 16 + l15];
#pragma unroll
    for (int mt = 0; mt < 4; mt++)
#pragma unroll
      for (int nt = 0; nt < 2; nt++) {
        float bv = nt ? bv1 : bv0;
        int kh = wid * 32 + nt * 16 + l15;
#pragma unroll
        for (int rr = 0; rr < 4; rr++) {
          float v = hacc[mt][nt][rr] + bv;
          A2sh[(mt * 16 + lhi * 4 + rr) * A2S + kh] = f2bf(fast_gelu(v));
        }
      }
    __builtin_amdgcn_s_barrier();
    // GEMM2: out[64 tok][64 oc-per-wave] += A2[64][128] x w2t-slice
#pragma unroll
    for (int k2 = 0; k2 < 4; k2++) {
      short8 a2[4], bf2v[4];
#pragma unroll
      for (int mt = 0; mt < 4; mt++) {
        const unsigned short* p = &A2sh[(mt * 16 + l15) * A2S + k2 * 32 + lhi * 8];
        short4v lo = *(const short4v*)p;
        short4v hi = *(const short4v*)(p + 4);
        a2[mt] = (short8){lo[0], lo[1], lo[2], lo[3], hi[0], hi[1], hi[2], hi[3]};
      }
#pragma unroll
      for (int nt = 0; nt < 4; nt++)
        bf2v[nt] = *(const short8*)(w2t + (size_t)(wid * 64 + nt * 16 + l15) * 1024 +
                                    hs * 128 + k2 * 32 + lhi * 8);
#pragma unroll
      for (int mt = 0; mt < 4; mt++)
#pragma unroll
        for (int nt = 0; nt < 4; nt++)
          oacc[mt][nt] = __builtin_amdgcn_mfma_f32_16x16x32_bf16(a2[mt], bf2v[nt], oacc[mt][nt], 0, 0, 0);
    }
    __builtin_amdgcn_s_barrier();   // A2sh reuse next slice
  }

  // epilogue: + b2 + x2 residual, departition scatter (f32x4)
#pragma unroll
  for (int mt = 0; mt < 4; mt++) {
#pragma unroll
    for (int nt = 0; nt < 4; nt++) {
      size_t gm0 = m0 + mt * 16 + lhi * 4;
      int gn = wid * 64 + nt * 16 + l15;
      int bi = (int)(gm0 >> 12), gg = (int)((gm0 >> 6) & 63), s0 = (int)(gm0 & 63);
      size_t sp = (size_t)((gg >> 3) * 8 + (s0 >> 3)) * 64 + (gg & 7) * 8 + (s0 & 7);
      f32x4 o4;
#pragma unroll
      for (int r = 0; r < 4; r++)
        o4[r] = oacc[mt][nt][r] + b2[gn] + bf2f(x2[(gm0 + r) * 256 + gn]);
      *(f32x4*)(&out[((size_t)(bi * 256 + gn)) * 4096 + sp]) = o4;
    }
  }
}

// ---- attention: one wave per (window, head) ----
__global__ __launch_bounds__(64) void attn_k(
    const unsigned short* __restrict__ qkv, const float* __restrict__ relb,
    unsigned short* __restrict__ o) {
  __shared__ __align__(16) unsigned short p_lds[64 * 72];
  __shared__ __align__(16) unsigned short vt_lds[32 * 72];
  const int l = threadIdx.x;
  const int l15 = l & 15, lhi = l >> 4;
  const int w = blockIdx.x, head = blockIdx.y;
  const unsigned short* base = qkv + (size_t)w * 64 * 768 + head * 32;

  short8 aq[4], bk[4];
#pragma unroll
  for (int t = 0; t < 4; t++) {
    aq[t] = *(const short8*)(base + (t * 16 + l15) * 768 + lhi * 8);
    bk[t] = *(const short8*)(base + 256 + (t * 16 + l15) * 768 + lhi * 8);
  }
  f32x4 s[4][4];
#pragma unroll
  for (int i = 0; i < 4; i++)
#pragma unroll
    for (int j = 0; j < 4; j++) s[i][j] = (f32x4){0.f, 0.f, 0.f, 0.f};
#pragma unroll
  for (int mt = 0; mt < 4; mt++)
#pragma unroll
    for (int nt = 0; nt < 4; nt++)
      s[mt][nt] = __builtin_amdgcn_mfma_f32_16x16x32_bf16(aq[mt], bk[nt], s[mt][nt], 0, 0, 0);

  const float* rb = relb + head * 4096;
  float rsum[4][4];
#pragma unroll
  for (int mt = 0; mt < 4; mt++) {
#pragma unroll
    for (int r = 0; r < 4; r++) {
      int row = mt * 16 + lhi * 4 + r;
      float vv[4];
      float vmax = -1e30f;
#pragma unroll
      for (int nt = 0; nt < 4; nt++) {
        int col = nt * 16 + l15;
        float v = s[mt][nt][r] * SCALE_F + rb[row * 64 + col];
        vv[nt] = v;
        vmax = fmaxf(vmax, v);
      }
#pragma unroll
      for (int d = 1; d < 16; d <<= 1) vmax = fmaxf(vmax, __shfl_xor(vmax, d, 64));
      float sum = 0.f;
#pragma unroll
      for (int nt = 0; nt < 4; nt++) {
        float p = __expf(vv[nt] - vmax);
        sum += p;
        p_lds[row * 72 + nt * 16 + l15] = f2bf(p);
      }
#pragma unroll
      for (int d = 1; d < 16; d <<= 1) sum += __shfl_xor(sum, d, 64);
      rsum[mt][r] = 1.f / sum;
    }
  }

  // stage v^T: vt[dh][token]
#pragma unroll
  for (int j = 0; j < 4; j++) {
    short8 vv = *(const short8*)(base + 512 + l * 768 + j * 8);
#pragma unroll
    for (int e = 0; e < 8; e++)
      vt_lds[(j * 8 + e) * 72 + l] = (unsigned short)vv[e];
  }
  __syncthreads();

  f32x4 o2[4][2];
#pragma unroll
  for (int i = 0; i < 4; i++) { o2[i][0] = (f32x4){0.f,0.f,0.f,0.f}; o2[i][1] = (f32x4){0.f,0.f,0.f,0.f}; }
#pragma unroll
  for (int ks = 0; ks < 2; ks++) {
    short8 ap[4], bv[2];
#pragma unroll
    for (int t = 0; t < 4; t++)
      ap[t] = *(const short8*)(&p_lds[(t * 16 + l15) * 72 + ks * 32 + lhi * 8]);
#pragma unroll
    for (int t = 0; t < 2; t++)
      bv[t] = *(const short8*)(&vt_lds[(t * 16 + l15) * 72 + ks * 32 + lhi * 8]);
#pragma unroll
    for (int mt = 0; mt < 4; mt++)
#pragma unroll
      for (int n2 = 0; n2 < 2; n2++)
        o2[mt][n2] = __builtin_amdgcn_mfma_f32_16x16x32_bf16(ap[mt], bv[n2], o2[mt][n2], 0, 0, 0);
  }
#pragma unroll
  for (int mt = 0; mt < 4; mt++)
#pragma unroll
    for (int n2 = 0; n2 < 2; n2++)
#pragma unroll
      for (int r = 0; r < 4; r++) {
        int row = mt * 16 + lhi * 4 + r;
        int dh = n2 * 16 + l15;
        o[((size_t)w * 64 + row) * 256 + head * 32 + dh] = f2bf(o2[mt][n2][r] * rsum[mt][r]);
      }
}

extern "C" void kernel_launch(void* const* d_in, const int* in_sizes, int n_in,
                              void* d_out, int out_size, void* d_ws, size_t ws_size,
                              hipStream_t stream) {
  (void)in_sizes; (void)n_in; (void)out_size;
  const float* x          = (const float*)d_in[0];
  const float* ln1_g      = (const float*)d_in[1];
  const float* ln1_b      = (const float*)d_in[2];
  const float* qkv_w      = (const float*)d_in[3];
  const float* qkv_b      = (const float*)d_in[4];
  const float* merge_w    = (const float*)d_in[5];
  const float* merge_b    = (const float*)d_in[6];
  const float* bias_table = (const float*)d_in[7];
  const float* ln2_g      = (const float*)d_in[8];
  const float* ln2_b      = (const float*)d_in[9];
  const float* mlp_w1     = (const float*)d_in[10];
  const float* mlp_b1     = (const float*)d_in[11];
  const float* mlp_w2     = (const float*)d_in[12];
  const float* mlp_b2     = (const float*)d_in[13];

  const size_t MB = 1024ull * 1024ull;
  char* ws = (char*)d_ws;
  unsigned short* buf0 = (unsigned short*)(ws);             // 64 MiB: h -> attno -> h2
  unsigned short* x2   = (unsigned short*)(ws + 64 * MB);   // 64 MiB: bf16 residual-1
  unsigned short* wqkv = (unsigned short*)(ws + 128 * MB);  // [768][256] bf16
  unsigned short* wmrg = wqkv + 768 * 256;                  // [256][256]
  unsigned short* w1t  = wmrg + 256 * 256;                  // [1024][256]
  unsigned short* w2t  = w1t + 1024 * 256;                  // [256][1024]
  float* relb          = (float*)(w2t + 256 * 1024);        // [8][64][64] f32
  unsigned short* Cbuf = (unsigned short*)(ws + 130 * MB);  // qkv chunk scratch

  size_t avail = ws_size > 130 * MB ? ws_size - 130 * MB : 0;
  int wc = 64;                                   // windows per qkv/attn chunk
  {
    const int cands[3] = {512, 256, 128};
    for (int i = 0; i < 3; i++)
      if ((size_t)cands[i] * 64 * 768 * 2 <= avail) { wc = cands[i]; break; }
  }

  cast_wt<256, 768><<<768, 256, 0, stream>>>(qkv_w, wqkv);
  cast_wt<256, 256><<<256, 256, 0, stream>>>(merge_w, wmrg);
  cast_wt<256, 1024><<<1024, 256, 0, stream>>>(mlp_w1, w1t);
  cast_wt<1024, 256><<<1024, 256, 0, stream>>>(mlp_w2, w2t);
  build_relb<<<128, 256, 0, stream>>>(bias_table, relb);

  part_ln1<<<1024, 256, 0, stream>>>(x, ln1_g, ln1_b, buf0);

  for (int w0 = 0; w0 < 2048; w0 += wc) {
    gemm_qkv<<<dim3(wc * 64 / 128, 6), 256, 0, stream>>>(
        buf0 + (size_t)w0 * 64 * 256, wqkv, qkv_b, nullptr, Cbuf, 256, 768, 0);
    attn_k<<<dim3(wc, 8), 64, 0, stream>>>(Cbuf, relb, buf0 + (size_t)w0 * 64 * 256);
  }

  gemm_merge<<<dim3(1024, 2), 256, 0, stream>>>(
      buf0, wmrg, merge_b, x, x2, 256, 256, 0);

  ln2k<<<32768, 256, 0, stream>>>(x2, ln2_g, ln2_b, buf0);

  mlp_fused<<<2048, 256, 0, stream>>>(buf0, w1t, mlp_b1, w2t, mlp_b2, x2, (float*)d_out);
}